// Round 2
// baseline (363.112 us; speedup 1.0000x reference)
//
#include <hip/hip_runtime.h>
#include <stdint.h>

typedef unsigned short u16;
typedef unsigned int u32;
typedef short short8 __attribute__((ext_vector_type(8)));
typedef float f32x4 __attribute__((ext_vector_type(4)));
typedef u32 u32x4 __attribute__((ext_vector_type(4)));
typedef u32 u32x2 __attribute__((ext_vector_type(2)));

#define DEV static __device__ __forceinline__

constexpr int Bsz = 4, Lseq = 2048, Dm = 1024, Hn = 16, Dk = 64;
constexpr float LOG2E = 1.44269504088896340736f;

DEV u16 f2bf(float x) {
    u32 u = __builtin_bit_cast(u32, x);
    return (u16)((u + 0x7fffu + ((u >> 16) & 1u)) >> 16);
}
DEV float bf2f(u16 b) {
    u32 u = ((u32)b) << 16;
    return __builtin_bit_cast(float, u);
}

// load 8 consecutive fp32, round-to-nearest-even to bf16, pack as u32x4
DEV u32x4 ld8_cvt(const float* p) {
    f32x4 lo = *(const f32x4*)p;
    f32x4 hi = *(const f32x4*)(p + 4);
    u32x4 r;
    r[0] = (u32)f2bf(lo[0]) | ((u32)f2bf(lo[1]) << 16);
    r[1] = (u32)f2bf(lo[2]) | ((u32)f2bf(lo[3]) << 16);
    r[2] = (u32)f2bf(hi[0]) | ((u32)f2bf(hi[1]) << 16);
    r[3] = (u32)f2bf(hi[2]) | ((u32)f2bf(hi[3]) << 16);
    return r;
}

// ---------------------------------------------------------------------------
// GEMM: C[M,N] = X[M,K] @ W[N,K]^T + bias   (torch Linear, B^T layout)
// A32: X is fp32 (converted to bf16 during staging); else X is bf16 (u16).
// W and bias are always fp32. f32 accum via 16x16x32 bf16 MFMA.
// Tile 128x128, BK=32, 256 threads = 4 waves (2x2), wave tile 64x64.
// Double-buffered LDS, register staging (global->reg(cvt)->LDS).
// MODE 0: write bf16 headed layout [B,H,L,DK]  (Q/K/V projections, to ws)
// MODE 1: write fp32 row-major [M,N]           (output projection, to d_out)
// ---------------------------------------------------------------------------
template <int MODE, int A32>
__global__ __launch_bounds__(256) void gemm_bt(
    const void* __restrict__ Xv, const float* __restrict__ W,
    const float* __restrict__ bias, void* __restrict__ Cout, int Kdim)
{
    __shared__ u16 At[2][128 * 32];
    __shared__ u16 Bt[2][128 * 32];

    const int tid = threadIdx.x;
    const int lane = tid & 63, wid = tid >> 6;
    const int wr = wid >> 1, wc = wid & 1;
    const int mbase = blockIdx.x * 128, nbase = blockIdx.y * 128;

    f32x4 acc[4][4];
#pragma unroll
    for (int i = 0; i < 4; i++)
#pragma unroll
        for (int j = 0; j < 4; j++) acc[i][j] = (f32x4)0.f;

    const int NT = Kdim >> 5;

    u32x4 va[2], vb[2];
    // prologue: stage k-tile 0 into buf 0
#pragma unroll
    for (int i = 0; i < 2; i++) {
        int idx = i * 256 + tid;
        int row = idx >> 2, seg = idx & 3;
        if (A32)
            va[i] = ld8_cvt((const float*)Xv + (long)(mbase + row) * Kdim + seg * 8);
        else
            va[i] = *(const u32x4*)((const u16*)Xv + (long)(mbase + row) * Kdim + seg * 8);
        vb[i] = ld8_cvt(W + (long)(nbase + row) * Kdim + seg * 8);
    }
#pragma unroll
    for (int i = 0; i < 2; i++) {
        int idx = i * 256 + tid;
        *(u32x4*)&At[0][idx * 8] = va[i];
        *(u32x4*)&Bt[0][idx * 8] = vb[i];
    }
    __syncthreads();

    for (int kt = 0; kt < NT; kt++) {
        const int cur = kt & 1;
        const bool more = (kt + 1 < NT);
        // issue next tile's global loads early (latency hides under MFMA)
        if (more) {
#pragma unroll
            for (int i = 0; i < 2; i++) {
                int idx = i * 256 + tid;
                int row = idx >> 2, seg = idx & 3;
                long ko = (long)(kt + 1) * 32 + seg * 8;
                if (A32)
                    va[i] = ld8_cvt((const float*)Xv + (long)(mbase + row) * Kdim + ko);
                else
                    va[i] = *(const u32x4*)((const u16*)Xv + (long)(mbase + row) * Kdim + ko);
                vb[i] = ld8_cvt(W + (long)(nbase + row) * Kdim + ko);
            }
        }
        // compute current tile
        short8 af[4], bfr[4];
#pragma unroll
        for (int mf = 0; mf < 4; mf++)
            af[mf] = *(const short8*)&At[cur][(wr * 64 + mf * 16 + (lane & 15)) * 32 + (lane >> 4) * 8];
#pragma unroll
        for (int nf = 0; nf < 4; nf++)
            bfr[nf] = *(const short8*)&Bt[cur][(wc * 64 + nf * 16 + (lane & 15)) * 32 + (lane >> 4) * 8];
#pragma unroll
        for (int mf = 0; mf < 4; mf++)
#pragma unroll
            for (int nf = 0; nf < 4; nf++)
                acc[mf][nf] = __builtin_amdgcn_mfma_f32_16x16x32_bf16(af[mf], bfr[nf], acc[mf][nf], 0, 0, 0);
        // write staged regs into the other buffer
        if (more) {
#pragma unroll
            for (int i = 0; i < 2; i++) {
                int idx = i * 256 + tid;
                *(u32x4*)&At[cur ^ 1][idx * 8] = va[i];
                *(u32x4*)&Bt[cur ^ 1][idx * 8] = vb[i];
            }
        }
        __syncthreads();
    }

    // epilogue: bias + store
#pragma unroll
    for (int nf = 0; nf < 4; nf++) {
        const int n = nbase + wc * 64 + nf * 16 + (lane & 15);
        const float bv = bias[n];
#pragma unroll
        for (int mf = 0; mf < 4; mf++) {
            const int m0 = mbase + wr * 64 + mf * 16 + (lane >> 4) * 4;
#pragma unroll
            for (int r = 0; r < 4; r++) {
                const int m = m0 + r;
                const float v = acc[mf][nf][r] + bv;
                if (MODE == 0) {
                    // m = b*L + l ; n = h*DK + dk -> bf16 [B,H,L,DK]
                    int b = m >> 11, l = m & 2047, h = n >> 6, dk = n & 63;
                    long addr = ((long)(b * Hn + h) * Lseq + l) * Dk + dk;
                    ((u16*)Cout)[addr] = f2bf(v);
                } else {
                    ((float*)Cout)[(long)m * Dm + n] = v;
                }
            }
        }
    }
}

// ---------------------------------------------------------------------------
// Flash attention (causal). Grid: (L/128 q-tiles, B*H). Block 256 = 4 waves.
// Wave w owns q rows [qt*128 + w*32, +32) as 2 q-fragments of 16.
// Swapped QK^T: S^T = mfma(K, Q) -> lane holds col q = lane&15 (stats lane-
// local). Swapped PV: ctx^T = mfma(V^T, P^T) accumulates with col q = lane&15,
// so the online-softmax rescale needs no cross-lane traffic.
// K tile [64kv][64dk] linear LDS; V transpose-staged to Vt[dk][kv] with XOR
// swizzle kv^=(dk>>3)<<3; P per-wave [32q][64kv] with XOR swizzle
// kv^=(q&7)<<3 (b64 packed writes). All buffers here are bf16 (internal).
// ---------------------------------------------------------------------------
__global__ __launch_bounds__(256) void attn_fwd(
    const u16* __restrict__ Qb, const u16* __restrict__ Kb,
    const u16* __restrict__ Vb, u16* __restrict__ Ctx)
{
    __shared__ u16 Kt[64 * 64];
    __shared__ u16 Vt[64 * 64];
    __shared__ u16 Pq[4][32 * 64];

    const int tid = threadIdx.x, lane = tid & 63, w = tid >> 6;
    const int qt = blockIdx.x, bh = blockIdx.y;
    const long base = (long)bh * Lseq * Dk;
    const int qw = qt * 128 + w * 32;

    // Q fragments in registers: [qf][ks] (B-operand pattern = row-major read)
    short8 qfr[2][2];
#pragma unroll
    for (int qf = 0; qf < 2; qf++)
#pragma unroll
        for (int ks = 0; ks < 2; ks++) {
            int q = qw + qf * 16 + (lane & 15);
            int d0 = ks * 32 + (lane >> 4) * 8;
            qfr[qf][ks] = *(const short8*)(Qb + base + (long)q * Dk + d0);
        }

    f32x4 accT[4][2];  // [dkf][qf], ctx^T: row = dk, col = q
#pragma unroll
    for (int i = 0; i < 4; i++)
#pragma unroll
        for (int j = 0; j < 2; j++) accT[i][j] = (f32x4)0.f;
    float m_run[2] = {-__builtin_inff(), -__builtin_inff()};
    float l_run[2] = {0.f, 0.f};

    const int nkv = qt * 2 + 2;  // kv tiles up to the block diagonal
    for (int kvt = 0; kvt < nkv; kvt++) {
        const int kvbase = kvt * 64;
        // ---- stage K (linear) and V (transposed + swizzled)
#pragma unroll
        for (int i = 0; i < 2; i++) {
            int idx = i * 256 + tid;
            int kv = idx >> 3, seg = idx & 7;
            u32x4 kreg = *(const u32x4*)(Kb + base + (long)(kvbase + kv) * Dk + seg * 8);
            *(u32x4*)&Kt[idx * 8] = kreg;
        }
#pragma unroll
        for (int i = 0; i < 2; i++) {
            int idx = i * 256 + tid;
            int kv = idx >> 3, db = (idx & 7) * 8;
            u32x4 vv = *(const u32x4*)(Vb + base + (long)(kvbase + kv) * Dk + db);
            const u16* pv = (const u16*)&vv;
            int kvs = kv ^ ((idx & 7) << 3);
#pragma unroll
            for (int j = 0; j < 8; j++) Vt[(db + j) * 64 + kvs] = pv[j];
        }
        __syncthreads();

        // ---- S^T = K @ Q^T  frags [kvf][qf]
        f32x4 st[4][2];
#pragma unroll
        for (int i = 0; i < 4; i++)
#pragma unroll
            for (int j = 0; j < 2; j++) st[i][j] = (f32x4)0.f;
#pragma unroll
        for (int ks = 0; ks < 2; ks++) {
            short8 kf[4];
#pragma unroll
            for (int kvf = 0; kvf < 4; kvf++)
                kf[kvf] = *(const short8*)&Kt[(kvf * 16 + (lane & 15)) * 64 + ks * 32 + (lane >> 4) * 8];
#pragma unroll
            for (int kvf = 0; kvf < 4; kvf++)
#pragma unroll
                for (int qf = 0; qf < 2; qf++)
                    st[kvf][qf] = __builtin_amdgcn_mfma_f32_16x16x32_bf16(kf[kvf], qfr[qf][ks], st[kvf][qf], 0, 0, 0);
        }

        // ---- scale + causal mask (wave-uniform skip when fully below diag)
        const bool need_mask = (kvbase + 63) > qw;
#pragma unroll
        for (int qf = 0; qf < 2; qf++) {
            const int q = qw + qf * 16 + (lane & 15);
#pragma unroll
            for (int kvf = 0; kvf < 4; kvf++)
#pragma unroll
                for (int r = 0; r < 4; r++) {
                    float s = st[kvf][qf][r] * 0.125f;
                    if (need_mask) {
                        int kv = kvbase + kvf * 16 + (lane >> 4) * 4 + r;
                        if (kv > q) s = -1e30f;
                    }
                    st[kvf][qf][r] = s;
                }
        }

        // ---- online softmax per q (col = lane&15), P -> LDS
#pragma unroll
        for (int qf = 0; qf < 2; qf++) {
            float tmax = st[0][qf][0];
#pragma unroll
            for (int kvf = 0; kvf < 4; kvf++)
#pragma unroll
                for (int r = 0; r < 4; r++) tmax = fmaxf(tmax, st[kvf][qf][r]);
            tmax = fmaxf(tmax, __shfl_xor(tmax, 16, 64));
            tmax = fmaxf(tmax, __shfl_xor(tmax, 32, 64));
            const float mnew = fmaxf(m_run[qf], tmax);
            const float sc = __builtin_exp2f((m_run[qf] - mnew) * LOG2E);
            m_run[qf] = mnew;
            float tsum = 0.f;
#pragma unroll
            for (int kvf = 0; kvf < 4; kvf++)
#pragma unroll
                for (int r = 0; r < 4; r++) {
                    float p = __builtin_exp2f((st[kvf][qf][r] - mnew) * LOG2E);
                    st[kvf][qf][r] = p;
                    tsum += p;
                }
            tsum += __shfl_xor(tsum, 16, 64);
            tsum += __shfl_xor(tsum, 32, 64);
            l_run[qf] = l_run[qf] * sc + tsum;
#pragma unroll
            for (int dkf = 0; dkf < 4; dkf++)
#pragma unroll
                for (int r = 0; r < 4; r++) accT[dkf][qf][r] *= sc;
            // pack P (4 consecutive kv per lane) -> b64 swizzled write
            const int qrow = qf * 16 + (lane & 15);
#pragma unroll
            for (int kvf = 0; kvf < 4; kvf++) {
                u32x2 pk;
                pk[0] = (u32)f2bf(st[kvf][qf][0]) | ((u32)f2bf(st[kvf][qf][1]) << 16);
                pk[1] = (u32)f2bf(st[kvf][qf][2]) | ((u32)f2bf(st[kvf][qf][3]) << 16);
                int kvi = (kvf * 16 + (lane >> 4) * 4) ^ ((lane & 7) << 3);
                *(u32x2*)&Pq[w][qrow * 64 + kvi] = pk;
            }
        }

        // ---- PV: ctx^T += V^T @ P^T
#pragma unroll
        for (int kf2 = 0; kf2 < 2; kf2++) {
            short8 vfr[4];
#pragma unroll
            for (int dkf = 0; dkf < 4; dkf++) {
                int dk = dkf * 16 + (lane & 15);
                int kvi = (kf2 * 32 + ((lane >> 4) * 8)) ^ ((dk >> 3) << 3);
                vfr[dkf] = *(const short8*)&Vt[dk * 64 + kvi];
            }
            short8 pfr[2];
#pragma unroll
            for (int qf = 0; qf < 2; qf++) {
                int qrow = qf * 16 + (lane & 15);
                int kvi = (kf2 * 32 + ((lane >> 4) * 8)) ^ ((lane & 7) << 3);
                pfr[qf] = *(const short8*)&Pq[w][qrow * 64 + kvi];
            }
#pragma unroll
            for (int dkf = 0; dkf < 4; dkf++)
#pragma unroll
                for (int qf = 0; qf < 2; qf++)
                    accT[dkf][qf] = __builtin_amdgcn_mfma_f32_16x16x32_bf16(vfr[dkf], pfr[qf], accT[dkf][qf], 0, 0, 0);
        }
        __syncthreads();
    }

    // ---- epilogue: divide by l, write ctx[b][l=q][h][dk] (bf16 [B,L,D])
    const int b = bh >> 4, h = bh & 15;
#pragma unroll
    for (int qf = 0; qf < 2; qf++) {
        const float inv = 1.f / l_run[qf];
        const int q = qw + qf * 16 + (lane & 15);
#pragma unroll
        for (int dkf = 0; dkf < 4; dkf++) {
            const int dk0 = dkf * 16 + (lane >> 4) * 4;
            u32x2 o;
            o[0] = (u32)f2bf(accT[dkf][qf][0] * inv) | ((u32)f2bf(accT[dkf][qf][1] * inv) << 16);
            o[1] = (u32)f2bf(accT[dkf][qf][2] * inv) | ((u32)f2bf(accT[dkf][qf][3] * inv) << 16);
            long addr = ((long)b * Lseq + q) * Dm + h * Dk + dk0;
            *(u32x2*)(Ctx + addr) = o;
        }
    }
}

// ---------------------------------------------------------------------------
extern "C" void kernel_launch(void* const* d_in, const int* in_sizes, int n_in,
                              void* d_out, int out_size, void* d_ws, size_t ws_size,
                              hipStream_t stream)
{
    const float* query = (const float*)d_in[0];
    const float* key_  = (const float*)d_in[1];
    const float* value = (const float*)d_in[2];
    const float* Wq = (const float*)d_in[3];
    const float* bq = (const float*)d_in[4];
    const float* Wk = (const float*)d_in[5];
    const float* bk = (const float*)d_in[6];
    const float* Wv = (const float*)d_in[7];
    const float* bv = (const float*)d_in[8];
    const float* Wo = (const float*)d_in[9];
    const float* bo = (const float*)d_in[10];
    // d_in[11] = attn_mask (bool causal) — derived from indices instead.

    float* out = (float*)d_out;
    const size_t tens = (size_t)Bsz * Lseq * Dm;  // 8.4M elements
    u16* Qb = (u16*)d_ws;        // bf16 [B,H,L,DK]
    u16* Kb = Qb + tens;         // bf16 [B,H,L,DK]
    u16* Vb = Kb + tens;         // bf16 [B,H,L,DK]
    u16* Cx = Vb + tens;         // bf16 [B,L,D]
    // needs 4*16.8 MB = 67 MB of workspace

    dim3 g(64, 8), blk(256);
    gemm_bt<0, 1><<<g, blk, 0, stream>>>(query, Wq, bq, Qb, Dm);
    gemm_bt<0, 1><<<g, blk, 0, stream>>>(key_,  Wk, bk, Kb, Dm);
    gemm_bt<0, 1><<<g, blk, 0, stream>>>(value, Wv, bv, Vb, Dm);
    attn_fwd<<<dim3(Lseq / 128, Bsz * Hn), blk, 0, stream>>>(Qb, Kb, Vb, Cx);
    gemm_bt<1, 0><<<g, blk, 0, stream>>>(Cx, Wo, bo, out, Dm);
}

// Round 4
// 254.989 us; speedup vs baseline: 1.4240x; 1.4240x over previous
//
#include <hip/hip_runtime.h>
#include <hip/hip_bf16.h>
#include <stdint.h>

typedef unsigned short u16;
typedef unsigned int u32;
typedef short short8 __attribute__((ext_vector_type(8)));
typedef float f32x4 __attribute__((ext_vector_type(4)));
typedef u32 u32x4 __attribute__((ext_vector_type(4)));
typedef u32 u32x2 __attribute__((ext_vector_type(2)));

#define DEV static __device__ __forceinline__

constexpr int Bsz = 4, Lseq = 2048, Dm = 1024, Hn = 16, Dk = 64;
constexpr float LOG2E = 1.44269504088896340736f;
constexpr float QSCALE = 0.125f * LOG2E;  // folded into Q projection

DEV u16 f2bf(float x) {
    u32 u = __builtin_bit_cast(u32, x);
    return (u16)((u + 0x7fffu + ((u >> 16) & 1u)) >> 16);
}

// pack 2 fp32 -> 2 bf16 in a u32 via HW v_cvt_pk_bf16_f32 path
DEV u32 pk2(float a, float b) {
    __hip_bfloat162 h = __float22bfloat162_rn(float2{a, b});
    u32 r;
    __builtin_memcpy(&r, &h, 4);
    return r;
}

// load 8 consecutive fp32, RNE to bf16, pack as u32x4
DEV u32x4 ld8_cvt(const float* p) {
    f32x4 lo = *(const f32x4*)p;
    f32x4 hi = *(const f32x4*)(p + 4);
    u32x4 r;
    r[0] = pk2(lo[0], lo[1]);
    r[1] = pk2(lo[2], lo[3]);
    r[2] = pk2(hi[0], hi[1]);
    r[3] = pk2(hi[2], hi[3]);
    return r;
}

// ---------------------------------------------------------------------------
// GEMM: C[M,N] = (X[M,K] @ W[N,K]^T + bias) * scale   (torch Linear, B^T)
// A32: X fp32 (cvt to bf16 in staging) else bf16. W/bias always fp32.
// 128x128 tile, BK=32, 4 waves (2x2), wave tile 64x64, dbuf LDS, reg staging.
// MODE 0: bf16 headed [B,H,L,DK] out;  MODE 1: fp32 row-major [M,N] out.
// ---------------------------------------------------------------------------
template <int MODE, int A32>
__global__ __launch_bounds__(256) void gemm_bt(
    const void* __restrict__ Xv, const float* __restrict__ W,
    const float* __restrict__ bias, void* __restrict__ Cout, int Kdim,
    float scale)
{
    __shared__ u16 At[2][128 * 32];
    __shared__ u16 Bt[2][128 * 32];

    const int tid = threadIdx.x;
    const int lane = tid & 63, wid = tid >> 6;
    const int wr = wid >> 1, wc = wid & 1;
    const int mbase = blockIdx.x * 128, nbase = blockIdx.y * 128;

    f32x4 acc[4][4];
#pragma unroll
    for (int i = 0; i < 4; i++)
#pragma unroll
        for (int j = 0; j < 4; j++) acc[i][j] = (f32x4)0.f;

    const int NT = Kdim >> 5;

    u32x4 va[2], vb[2];
#pragma unroll
    for (int i = 0; i < 2; i++) {
        int idx = i * 256 + tid;
        int row = idx >> 2, seg = idx & 3;
        if (A32)
            va[i] = ld8_cvt((const float*)Xv + (long)(mbase + row) * Kdim + seg * 8);
        else
            va[i] = *(const u32x4*)((const u16*)Xv + (long)(mbase + row) * Kdim + seg * 8);
        vb[i] = ld8_cvt(W + (long)(nbase + row) * Kdim + seg * 8);
    }
#pragma unroll
    for (int i = 0; i < 2; i++) {
        int idx = i * 256 + tid;
        *(u32x4*)&At[0][idx * 8] = va[i];
        *(u32x4*)&Bt[0][idx * 8] = vb[i];
    }
    __syncthreads();

    for (int kt = 0; kt < NT; kt++) {
        const int cur = kt & 1;
        const bool more = (kt + 1 < NT);
        if (more) {
#pragma unroll
            for (int i = 0; i < 2; i++) {
                int idx = i * 256 + tid;
                int row = idx >> 2, seg = idx & 3;
                long ko = (long)(kt + 1) * 32 + seg * 8;
                if (A32)
                    va[i] = ld8_cvt((const float*)Xv + (long)(mbase + row) * Kdim + ko);
                else
                    va[i] = *(const u32x4*)((const u16*)Xv + (long)(mbase + row) * Kdim + ko);
                vb[i] = ld8_cvt(W + (long)(nbase + row) * Kdim + ko);
            }
        }
        short8 af[4], bfr[4];
#pragma unroll
        for (int mf = 0; mf < 4; mf++)
            af[mf] = *(const short8*)&At[cur][(wr * 64 + mf * 16 + (lane & 15)) * 32 + (lane >> 4) * 8];
#pragma unroll
        for (int nf = 0; nf < 4; nf++)
            bfr[nf] = *(const short8*)&Bt[cur][(wc * 64 + nf * 16 + (lane & 15)) * 32 + (lane >> 4) * 8];
#pragma unroll
        for (int mf = 0; mf < 4; mf++)
#pragma unroll
            for (int nf = 0; nf < 4; nf++)
                acc[mf][nf] = __builtin_amdgcn_mfma_f32_16x16x32_bf16(af[mf], bfr[nf], acc[mf][nf], 0, 0, 0);
        if (more) {
#pragma unroll
            for (int i = 0; i < 2; i++) {
                int idx = i * 256 + tid;
                *(u32x4*)&At[cur ^ 1][idx * 8] = va[i];
                *(u32x4*)&Bt[cur ^ 1][idx * 8] = vb[i];
            }
        }
        __syncthreads();
    }

#pragma unroll
    for (int nf = 0; nf < 4; nf++) {
        const int n = nbase + wc * 64 + nf * 16 + (lane & 15);
        const float bv = bias[n];
#pragma unroll
        for (int mf = 0; mf < 4; mf++) {
            const int m0 = mbase + wr * 64 + mf * 16 + (lane >> 4) * 4;
#pragma unroll
            for (int r = 0; r < 4; r++) {
                const int m = m0 + r;
                const float v = (acc[mf][nf][r] + bv) * scale;
                if (MODE == 0) {
                    int b = m >> 11, l = m & 2047, h = n >> 6, dk = n & 63;
                    long addr = ((long)(b * Hn + h) * Lseq + l) * Dk + dk;
                    ((u16*)Cout)[addr] = f2bf(v);
                } else {
                    ((float*)Cout)[(long)m * Dm + n] = v;
                }
            }
        }
    }
}

// ---------------------------------------------------------------------------
// Flash attention (causal), base-2 softmax domain (Q pre-scaled by 1/8*log2e).
// Grid: (B*H, L/128) with qt REVERSED (heavy blocks dispatch first).
// Block 256 = 4 waves; wave w owns q rows [qt*128+w*32, +32).
// Double-buffered K/V LDS (one barrier/iter); stage loads issued before QK^T.
// K tile: Kt[kv][d ^ ((kv&7)<<3)]               (conflict-free write+read)
// V tile (transposed): Vt[d][kv ^ (((d&7)^(d>>3))<<3)]  (c-f write+read)
// P per-wave [32q][64kv], col ^ ((q&7)<<3).
// Waves skip compute on fully-masked tiles (wave-uniform; still barrier).
// ---------------------------------------------------------------------------
__global__ __launch_bounds__(256) void attn_fwd(
    const u16* __restrict__ Qb, const u16* __restrict__ Kb,
    const u16* __restrict__ Vb, u16* __restrict__ Ctx)
{
    __shared__ u16 Kt[2][64 * 64];
    __shared__ u16 Vt[2][64 * 64];
    __shared__ u16 Pq[4][32 * 64];

    const int tid = threadIdx.x, lane = tid & 63, w = tid >> 6;
    const int qt = gridDim.y - 1 - blockIdx.y;  // heavy-first
    const int bh = blockIdx.x;
    const long base = (long)bh * Lseq * Dk;
    const int qw = qt * 128 + w * 32;

    const int skv = tid >> 3, seg = tid & 7;  // staging coords (+i*32 on kv)

    // Q fragments in registers (already scaled to log2 domain)
    short8 qfr[2][2];
#pragma unroll
    for (int qf = 0; qf < 2; qf++)
#pragma unroll
        for (int ks = 0; ks < 2; ks++) {
            int q = qw + qf * 16 + (lane & 15);
            int d0 = ks * 32 + (lane >> 4) * 8;
            qfr[qf][ks] = *(const short8*)(Qb + base + (long)q * Dk + d0);
        }

    f32x4 accT[4][2];  // ctx^T: [dkf][qf]
#pragma unroll
    for (int i = 0; i < 4; i++)
#pragma unroll
        for (int j = 0; j < 2; j++) accT[i][j] = (f32x4)0.f;
    float m_run[2] = {-__builtin_inff(), -__builtin_inff()};
    float l_run[2] = {0.f, 0.f};

    u32x4 kr[2], vr[2];
    // prologue: stage tile 0 into buf 0
#pragma unroll
    for (int i = 0; i < 2; i++) {
        int kv = i * 32 + skv;
        kr[i] = *(const u32x4*)(Kb + base + (long)kv * Dk + seg * 8);
        vr[i] = *(const u32x4*)(Vb + base + (long)kv * Dk + seg * 8);
    }
#pragma unroll
    for (int i = 0; i < 2; i++) {
        int kv = i * 32 + skv;
        *(u32x4*)&Kt[0][kv * 64 + ((seg * 8) ^ ((kv & 7) << 3))] = kr[i];
        const u16* pv = (const u16*)&vr[i];
#pragma unroll
        for (int j = 0; j < 8; j++) {
            int d = seg * 8 + j;
            Vt[0][d * 64 + (kv ^ ((((d & 7) ^ (d >> 3)) & 7) << 3))] = pv[j];
        }
    }
    __syncthreads();

    const int nkv = qt * 2 + 2;
    const int myn = ((qw + 31) >> 6) + 1;  // tiles this wave computes

    for (int kvt = 0; kvt < nkv; kvt++) {
        const int cur = kvt & 1;
        const bool more = (kvt + 1 < nkv);
        const int kvbase = kvt * 64;

        // issue next tile's global loads early (hide HBM under compute)
        if (more) {
#pragma unroll
            for (int i = 0; i < 2; i++) {
                int kv = i * 32 + skv;
                long row = (long)(kvbase + 64 + kv) * Dk;
                kr[i] = *(const u32x4*)(Kb + base + row + seg * 8);
                vr[i] = *(const u32x4*)(Vb + base + row + seg * 8);
            }
        }

        if (kvt < myn) {
            // ---- S^T = K @ Q^T  frags [kvf][qf] (log2 domain)
            f32x4 st[4][2];
#pragma unroll
            for (int i = 0; i < 4; i++)
#pragma unroll
                for (int j = 0; j < 2; j++) st[i][j] = (f32x4)0.f;
#pragma unroll
            for (int ks = 0; ks < 2; ks++) {
                short8 kf[4];
#pragma unroll
                for (int kvf = 0; kvf < 4; kvf++) {
                    int row = kvf * 16 + (lane & 15);
                    int d0 = ks * 32 + (lane >> 4) * 8;
                    kf[kvf] = *(const short8*)&Kt[cur][row * 64 + (d0 ^ ((row & 7) << 3))];
                }
#pragma unroll
                for (int kvf = 0; kvf < 4; kvf++)
#pragma unroll
                    for (int qf = 0; qf < 2; qf++)
                        st[kvf][qf] = __builtin_amdgcn_mfma_f32_16x16x32_bf16(kf[kvf], qfr[qf][ks], st[kvf][qf], 0, 0, 0);
            }

            // ---- causal mask (diagonal-crossing tiles only)
            const bool need_mask = (kvbase + 63) > qw;
            if (need_mask) {
#pragma unroll
                for (int qf = 0; qf < 2; qf++) {
                    const int q = qw + qf * 16 + (lane & 15);
#pragma unroll
                    for (int kvf = 0; kvf < 4; kvf++)
#pragma unroll
                        for (int r = 0; r < 4; r++) {
                            int kv = kvbase + kvf * 16 + (lane >> 4) * 4 + r;
                            if (kv > q) st[kvf][qf][r] = -1e30f;
                        }
                }
            }

            // ---- online softmax (base 2), P -> per-wave LDS
#pragma unroll
            for (int qf = 0; qf < 2; qf++) {
                float tmax = st[0][qf][0];
#pragma unroll
                for (int kvf = 0; kvf < 4; kvf++)
#pragma unroll
                    for (int r = 0; r < 4; r++) tmax = fmaxf(tmax, st[kvf][qf][r]);
                tmax = fmaxf(tmax, __shfl_xor(tmax, 16, 64));
                tmax = fmaxf(tmax, __shfl_xor(tmax, 32, 64));
                const float mnew = fmaxf(m_run[qf], tmax);
                const float sc = __builtin_exp2f(m_run[qf] - mnew);
                m_run[qf] = mnew;
                float tsum = 0.f;
#pragma unroll
                for (int kvf = 0; kvf < 4; kvf++)
#pragma unroll
                    for (int r = 0; r < 4; r++) {
                        float p = __builtin_exp2f(st[kvf][qf][r] - mnew);
                        st[kvf][qf][r] = p;
                        tsum += p;
                    }
                tsum += __shfl_xor(tsum, 16, 64);
                tsum += __shfl_xor(tsum, 32, 64);
                l_run[qf] = l_run[qf] * sc + tsum;
#pragma unroll
                for (int dkf = 0; dkf < 4; dkf++)
#pragma unroll
                    for (int r = 0; r < 4; r++) accT[dkf][qf][r] *= sc;
                const int qrow = qf * 16 + (lane & 15);
#pragma unroll
                for (int kvf = 0; kvf < 4; kvf++) {
                    u32x2 pk;
                    pk[0] = pk2(st[kvf][qf][0], st[kvf][qf][1]);
                    pk[1] = pk2(st[kvf][qf][2], st[kvf][qf][3]);
                    int kvi = (kvf * 16 + (lane >> 4) * 4) ^ ((lane & 7) << 3);
                    *(u32x2*)&Pq[w][qrow * 64 + kvi] = pk;
                }
            }

            // ---- PV: ctx^T += V^T @ P^T
#pragma unroll
            for (int kf2 = 0; kf2 < 2; kf2++) {
                short8 vfr[4];
#pragma unroll
                for (int dkf = 0; dkf < 4; dkf++) {
                    int d = dkf * 16 + (lane & 15);
                    int kvi = (kf2 * 32 + (lane >> 4) * 8) ^ ((((d & 7) ^ (d >> 3)) & 7) << 3);
                    vfr[dkf] = *(const short8*)&Vt[cur][d * 64 + kvi];
                }
                short8 pfr[2];
#pragma unroll
                for (int qf = 0; qf < 2; qf++) {
                    int qrow = qf * 16 + (lane & 15);
                    int kvi = (kf2 * 32 + (lane >> 4) * 8) ^ ((lane & 7) << 3);
                    pfr[qf] = *(const short8*)&Pq[w][qrow * 64 + kvi];
                }
#pragma unroll
                for (int dkf = 0; dkf < 4; dkf++)
#pragma unroll
                    for (int qf = 0; qf < 2; qf++)
                        accT[dkf][qf] = __builtin_amdgcn_mfma_f32_16x16x32_bf16(vfr[dkf], pfr[qf], accT[dkf][qf], 0, 0, 0);
            }
        }

        // write staged regs into the other buffer
        if (more) {
#pragma unroll
            for (int i = 0; i < 2; i++) {
                int kv = i * 32 + skv;
                *(u32x4*)&Kt[cur ^ 1][kv * 64 + ((seg * 8) ^ ((kv & 7) << 3))] = kr[i];
                const u16* pv = (const u16*)&vr[i];
#pragma unroll
                for (int j = 0; j < 8; j++) {
                    int d = seg * 8 + j;
                    Vt[cur ^ 1][d * 64 + (kv ^ ((((d & 7) ^ (d >> 3)) & 7) << 3))] = pv[j];
                }
            }
        }
        __syncthreads();
    }

    // ---- epilogue: divide by l, write ctx (bf16 [B,L,D])
    const int b = bh >> 4, h = bh & 15;
#pragma unroll
    for (int qf = 0; qf < 2; qf++) {
        const float inv = 1.f / l_run[qf];
        const int q = qw + qf * 16 + (lane & 15);
#pragma unroll
        for (int dkf = 0; dkf < 4; dkf++) {
            const int dk0 = dkf * 16 + (lane >> 4) * 4;
            u32x2 o;
            o[0] = pk2(accT[dkf][qf][0] * inv, accT[dkf][qf][1] * inv);
            o[1] = pk2(accT[dkf][qf][2] * inv, accT[dkf][qf][3] * inv);
            long addr = ((long)b * Lseq + q) * Dm + h * Dk + dk0;
            *(u32x2*)(Ctx + addr) = o;
        }
    }
}

// ---------------------------------------------------------------------------
extern "C" void kernel_launch(void* const* d_in, const int* in_sizes, int n_in,
                              void* d_out, int out_size, void* d_ws, size_t ws_size,
                              hipStream_t stream)
{
    const float* query = (const float*)d_in[0];
    const float* key_  = (const float*)d_in[1];
    const float* value = (const float*)d_in[2];
    const float* Wq = (const float*)d_in[3];
    const float* bq = (const float*)d_in[4];
    const float* Wk = (const float*)d_in[5];
    const float* bk = (const float*)d_in[6];
    const float* Wv = (const float*)d_in[7];
    const float* bv = (const float*)d_in[8];
    const float* Wo = (const float*)d_in[9];
    const float* bo = (const float*)d_in[10];
    // d_in[11] = attn_mask (bool causal) — derived from indices instead.

    float* out = (float*)d_out;
    const size_t tens = (size_t)Bsz * Lseq * Dm;  // 8.4M elements
    u16* Qb = (u16*)d_ws;        // bf16 [B,H,L,DK], pre-scaled by 1/8*log2e
    u16* Kb = Qb + tens;         // bf16 [B,H,L,DK]
    u16* Vb = Kb + tens;         // bf16 [B,H,L,DK]
    u16* Cx = Vb + tens;         // bf16 [B,L,D]

    dim3 g(64, 8), blk(256);
    gemm_bt<0, 1><<<g, blk, 0, stream>>>(query, Wq, bq, Qb, Dm, QSCALE);
    gemm_bt<0, 1><<<g, blk, 0, stream>>>(key_,  Wk, bk, Kb, Dm, 1.0f);
    gemm_bt<0, 1><<<g, blk, 0, stream>>>(value, Wv, bv, Vb, Dm, 1.0f);
    attn_fwd<<<dim3(Bsz * Hn, Lseq / 128), blk, 0, stream>>>(Qb, Kb, Vb, Cx);
    gemm_bt<1, 0><<<g, blk, 0, stream>>>(Cx, Wo, bo, out, Dm, 1.0f);
}

// Round 5
// 251.779 us; speedup vs baseline: 1.4422x; 1.0127x over previous
//
#include <hip/hip_runtime.h>
#include <hip/hip_bf16.h>
#include <stdint.h>

typedef unsigned short u16;
typedef unsigned int u32;
typedef short short8 __attribute__((ext_vector_type(8)));
typedef float f32x4 __attribute__((ext_vector_type(4)));
typedef u32 u32x4 __attribute__((ext_vector_type(4)));
typedef u32 u32x2 __attribute__((ext_vector_type(2)));

#define DEV static __device__ __forceinline__

constexpr int Bsz = 4, Lseq = 2048, Dm = 1024, Hn = 16, Dk = 64;
constexpr float LOG2E = 1.44269504088896340736f;
constexpr float QSCALE = 0.125f * LOG2E;  // folded into Q projection

DEV u16 f2bf(float x) {
    u32 u = __builtin_bit_cast(u32, x);
    return (u16)((u + 0x7fffu + ((u >> 16) & 1u)) >> 16);
}

// pack 2 fp32 -> 2 bf16 in a u32 via HW v_cvt_pk_bf16_f32 path
DEV u32 pk2(float a, float b) {
    __hip_bfloat162 h = __float22bfloat162_rn(float2{a, b});
    u32 r;
    __builtin_memcpy(&r, &h, 4);
    return r;
}

// load 8 consecutive fp32, RNE to bf16, pack as u32x4
DEV u32x4 ld8_cvt(const float* p) {
    f32x4 lo = *(const f32x4*)p;
    f32x4 hi = *(const f32x4*)(p + 4);
    u32x4 r;
    r[0] = pk2(lo[0], lo[1]);
    r[1] = pk2(lo[2], lo[3]);
    r[2] = pk2(hi[0], hi[1]);
    r[3] = pk2(hi[2], hi[3]);
    return r;
}

// async global->LDS, 16B per lane; lds dest must be wave-uniform base
DEV void glds16(const void* g, void* l) {
    __builtin_amdgcn_global_load_lds(
        (const __attribute__((address_space(1))) void*)g,
        (__attribute__((address_space(3))) void*)l, 16, 0, 0);
}

// ---------------------------------------------------------------------------
// fp32 -> bf16 conversion, 8 elems/thread
// ---------------------------------------------------------------------------
__global__ __launch_bounds__(256) void cvt_f2b(
    const float* __restrict__ s, u16* __restrict__ d, int n8)
{
    int i = blockIdx.x * 256 + threadIdx.x;
    if (i >= n8) return;
    ((u32x4*)d)[i] = ld8_cvt(s + (long)i * 8);
}

// ---------------------------------------------------------------------------
// All-bf16 GEMM (m97 structure): C = (A[M,K] @ W[N,K]^T + bias) * scale
// global_load_lds w=16 both operands, 128x128 tile, BK=32, 4 waves (2x2).
// MODE 0: bf16 headed [B,H,L,DK] out;  MODE 1: fp32 row-major [M,N] out.
// ---------------------------------------------------------------------------
template <int MODE>
__global__ __launch_bounds__(256) void gemm_glds(
    const u16* __restrict__ A, const u16* __restrict__ Bw,
    const float* __restrict__ bias, void* __restrict__ Cout, float scale)
{
    __shared__ u16 At[2][128 * 32];
    __shared__ u16 Bt[2][128 * 32];

    const int tid = threadIdx.x;
    const int lane = tid & 63, wid = tid >> 6;
    const int wr = wid >> 1, wc = wid & 1;
    const int mbase = blockIdx.x * 128, nbase = blockIdx.y * 128;

    f32x4 acc[4][4];
#pragma unroll
    for (int i = 0; i < 4; i++)
#pragma unroll
        for (int j = 0; j < 4; j++) acc[i][j] = (f32x4)0.f;

    const int srow = lane >> 2;        // row within 16-row section
    const int sseg = (lane & 3) * 8;   // col element offset

    auto stage = [&](int kt, int buf) {
#pragma unroll
        for (int c = 0; c < 2; c++) {
            const int sec = wid * 2 + c;
            const long ko = (long)kt * 32 + sseg;
            glds16(A + (long)(mbase + sec * 16 + srow) * Dm + ko, &At[buf][sec * 512]);
            glds16(Bw + (long)(nbase + sec * 16 + srow) * Dm + ko, &Bt[buf][sec * 512]);
        }
    };

    stage(0, 0);
    __syncthreads();

    for (int kt = 0; kt < 32; kt++) {
        const int cur = kt & 1;
        if (kt + 1 < 32) stage(kt + 1, cur ^ 1);
        short8 af[4], bfr[4];
#pragma unroll
        for (int mf = 0; mf < 4; mf++)
            af[mf] = *(const short8*)&At[cur][(wr * 64 + mf * 16 + (lane & 15)) * 32 + (lane >> 4) * 8];
#pragma unroll
        for (int nf = 0; nf < 4; nf++)
            bfr[nf] = *(const short8*)&Bt[cur][(wc * 64 + nf * 16 + (lane & 15)) * 32 + (lane >> 4) * 8];
        __builtin_amdgcn_s_setprio(1);
#pragma unroll
        for (int mf = 0; mf < 4; mf++)
#pragma unroll
            for (int nf = 0; nf < 4; nf++)
                acc[mf][nf] = __builtin_amdgcn_mfma_f32_16x16x32_bf16(af[mf], bfr[nf], acc[mf][nf], 0, 0, 0);
        __builtin_amdgcn_s_setprio(0);
        __syncthreads();  // drains vmcnt -> next buffer ready
    }

#pragma unroll
    for (int nf = 0; nf < 4; nf++) {
        const int n = nbase + wc * 64 + nf * 16 + (lane & 15);
        const float bv = bias[n];
#pragma unroll
        for (int mf = 0; mf < 4; mf++) {
            const int m0 = mbase + wr * 64 + mf * 16 + (lane >> 4) * 4;
#pragma unroll
            for (int r = 0; r < 4; r++) {
                const int m = m0 + r;
                const float v = (acc[mf][nf][r] + bv) * scale;
                if (MODE == 0) {
                    int b = m >> 11, l = m & 2047, h = n >> 6, dk = n & 63;
                    long addr = ((long)(b * Hn + h) * Lseq + l) * Dk + dk;
                    ((u16*)Cout)[addr] = f2bf(v);
                } else {
                    ((float*)Cout)[(long)m * Dm + n] = v;
                }
            }
        }
    }
}

// ---------------------------------------------------------------------------
// Fallback GEMM (R4, proven): reg staging + in-flight fp32->bf16 cvt
// ---------------------------------------------------------------------------
template <int MODE, int A32>
__global__ __launch_bounds__(256) void gemm_bt(
    const void* __restrict__ Xv, const float* __restrict__ W,
    const float* __restrict__ bias, void* __restrict__ Cout, int Kdim,
    float scale)
{
    __shared__ u16 At[2][128 * 32];
    __shared__ u16 Bt[2][128 * 32];

    const int tid = threadIdx.x;
    const int lane = tid & 63, wid = tid >> 6;
    const int wr = wid >> 1, wc = wid & 1;
    const int mbase = blockIdx.x * 128, nbase = blockIdx.y * 128;

    f32x4 acc[4][4];
#pragma unroll
    for (int i = 0; i < 4; i++)
#pragma unroll
        for (int j = 0; j < 4; j++) acc[i][j] = (f32x4)0.f;

    const int NT = Kdim >> 5;

    u32x4 va[2], vb[2];
#pragma unroll
    for (int i = 0; i < 2; i++) {
        int idx = i * 256 + tid;
        int row = idx >> 2, seg = idx & 3;
        if (A32)
            va[i] = ld8_cvt((const float*)Xv + (long)(mbase + row) * Kdim + seg * 8);
        else
            va[i] = *(const u32x4*)((const u16*)Xv + (long)(mbase + row) * Kdim + seg * 8);
        vb[i] = ld8_cvt(W + (long)(nbase + row) * Kdim + seg * 8);
    }
#pragma unroll
    for (int i = 0; i < 2; i++) {
        int idx = i * 256 + tid;
        *(u32x4*)&At[0][idx * 8] = va[i];
        *(u32x4*)&Bt[0][idx * 8] = vb[i];
    }
    __syncthreads();

    for (int kt = 0; kt < NT; kt++) {
        const int cur = kt & 1;
        const bool more = (kt + 1 < NT);
        if (more) {
#pragma unroll
            for (int i = 0; i < 2; i++) {
                int idx = i * 256 + tid;
                int row = idx >> 2, seg = idx & 3;
                long ko = (long)(kt + 1) * 32 + seg * 8;
                if (A32)
                    va[i] = ld8_cvt((const float*)Xv + (long)(mbase + row) * Kdim + ko);
                else
                    va[i] = *(const u32x4*)((const u16*)Xv + (long)(mbase + row) * Kdim + ko);
                vb[i] = ld8_cvt(W + (long)(nbase + row) * Kdim + ko);
            }
        }
        short8 af[4], bfr[4];
#pragma unroll
        for (int mf = 0; mf < 4; mf++)
            af[mf] = *(const short8*)&At[cur][(wr * 64 + mf * 16 + (lane & 15)) * 32 + (lane >> 4) * 8];
#pragma unroll
        for (int nf = 0; nf < 4; nf++)
            bfr[nf] = *(const short8*)&Bt[cur][(wc * 64 + nf * 16 + (lane & 15)) * 32 + (lane >> 4) * 8];
#pragma unroll
        for (int mf = 0; mf < 4; mf++)
#pragma unroll
            for (int nf = 0; nf < 4; nf++)
                acc[mf][nf] = __builtin_amdgcn_mfma_f32_16x16x32_bf16(af[mf], bfr[nf], acc[mf][nf], 0, 0, 0);
        if (more) {
#pragma unroll
            for (int i = 0; i < 2; i++) {
                int idx = i * 256 + tid;
                *(u32x4*)&At[cur ^ 1][idx * 8] = va[i];
                *(u32x4*)&Bt[cur ^ 1][idx * 8] = vb[i];
            }
        }
        __syncthreads();
    }

#pragma unroll
    for (int nf = 0; nf < 4; nf++) {
        const int n = nbase + wc * 64 + nf * 16 + (lane & 15);
        const float bv = bias[n];
#pragma unroll
        for (int mf = 0; mf < 4; mf++) {
            const int m0 = mbase + wr * 64 + mf * 16 + (lane >> 4) * 4;
#pragma unroll
            for (int r = 0; r < 4; r++) {
                const int m = m0 + r;
                const float v = (acc[mf][nf][r] + bv) * scale;
                if (MODE == 0) {
                    int b = m >> 11, l = m & 2047, h = n >> 6, dk = n & 63;
                    long addr = ((long)(b * Hn + h) * Lseq + l) * Dk + dk;
                    ((u16*)Cout)[addr] = f2bf(v);
                } else {
                    ((float*)Cout)[(long)m * Dm + n] = v;
                }
            }
        }
    }
}

// ---------------------------------------------------------------------------
// Flash attention (causal), base-2 softmax domain (Q pre-scaled by 1/8*log2e).
// Grid: (B*H, L/128), qt reversed (heavy-first). Block 256 = 4 waves,
// wave w owns q rows [qt*128+w*32, +32).
// K tile staged via global_load_lds w=16 with PRE-SWIZZLED global source:
//   LDS[kv][dcol] = K[kv][dcol ^ ((kv&7)<<3)]  (lane's 8 elems stay contiguous)
// V transpose-staged via regs: Vt[d][kv ^ (((d&7)^(d>>3))<<3)].
// Double-buffered, one barrier/iter. Softmax: lane-partial l (reduced once at
// end) + defer-max (skip rescale when tile max growth <= 8). setprio around
// MFMA clusters.
// ---------------------------------------------------------------------------
__global__ __launch_bounds__(256) void attn_fwd(
    const u16* __restrict__ Qb, const u16* __restrict__ Kb,
    const u16* __restrict__ Vb, u16* __restrict__ Ctx)
{
    __shared__ u16 Kt[2][64 * 64];
    __shared__ u16 Vt[2][64 * 64];
    __shared__ u16 Pq[4][32 * 64];

    const int tid = threadIdx.x, lane = tid & 63, w = tid >> 6;
    const int qt = gridDim.y - 1 - blockIdx.y;  // heavy-first
    const int bh = blockIdx.x;
    const long base = (long)bh * Lseq * Dk;
    const int qw = qt * 128 + w * 32;

    // K glds source coords (per wave): lane covers (kv = sec*8 + lane>>3, dcol=(lane&7)*8)
    const int krow_in_w = lane >> 3;              // 0..7
    const int kseg = lane & 7;                    // dcol block
    // V staging coords
    const int skv = tid >> 3, sdb = (tid & 7) * 8;

    // Q fragments in registers (already scaled to log2 domain)
    short8 qfr[2][2];
#pragma unroll
    for (int qf = 0; qf < 2; qf++)
#pragma unroll
        for (int ks = 0; ks < 2; ks++) {
            int q = qw + qf * 16 + (lane & 15);
            int d0 = ks * 32 + (lane >> 4) * 8;
            qfr[qf][ks] = *(const short8*)(Qb + base + (long)q * Dk + d0);
        }

    f32x4 accT[4][2];  // ctx^T: [dkf][qf]
#pragma unroll
    for (int i = 0; i < 4; i++)
#pragma unroll
        for (int j = 0; j < 2; j++) accT[i][j] = (f32x4)0.f;
    float m_run[2] = {-__builtin_inff(), -__builtin_inff()};
    float l_part[2] = {0.f, 0.f};

    auto stage_k = [&](int kvbase, int buf) {
#pragma unroll
        for (int c = 0; c < 2; c++) {
            int kv = w * 16 + c * 8 + krow_in_w;
            int d0 = ((kseg ^ (kv & 7)) * 8);  // pre-swizzled source column
            glds16(Kb + base + (long)(kvbase + kv) * Dk + d0,
                   &Kt[buf][(w * 16 + c * 8) * 64]);
        }
    };

    u32x4 vr[2];
    // prologue: tile 0
    stage_k(0, 0);
#pragma unroll
    for (int i = 0; i < 2; i++)
        vr[i] = *(const u32x4*)(Vb + base + (long)(i * 32 + skv) * Dk + sdb);
#pragma unroll
    for (int i = 0; i < 2; i++) {
        int kv = i * 32 + skv;
        const u16* pv = (const u16*)&vr[i];
#pragma unroll
        for (int j = 0; j < 8; j++) {
            int d = sdb + j;
            Vt[0][d * 64 + (kv ^ ((((d & 7) ^ (d >> 3)) & 7) << 3))] = pv[j];
        }
    }
    __syncthreads();

    const int nkv = qt * 2 + 2;
    const int myn = ((qw + 31) >> 6) + 1;  // tiles this wave computes

    for (int kvt = 0; kvt < nkv; kvt++) {
        const int cur = kvt & 1;
        const bool more = (kvt + 1 < nkv);
        const int kvbase = kvt * 64;

        // issue next tile's loads early (hide HBM under compute)
        if (more) {
            stage_k(kvbase + 64, cur ^ 1);
#pragma unroll
            for (int i = 0; i < 2; i++)
                vr[i] = *(const u32x4*)(Vb + base + (long)(kvbase + 64 + i * 32 + skv) * Dk + sdb);
        }

        if (kvt < myn) {
            // ---- S^T = K @ Q^T  frags [kvf][qf] (log2 domain)
            f32x4 st[4][2];
#pragma unroll
            for (int i = 0; i < 4; i++)
#pragma unroll
                for (int j = 0; j < 2; j++) st[i][j] = (f32x4)0.f;
            __builtin_amdgcn_s_setprio(1);
#pragma unroll
            for (int ks = 0; ks < 2; ks++) {
                short8 kf[4];
#pragma unroll
                for (int kvf = 0; kvf < 4; kvf++) {
                    int row = kvf * 16 + (lane & 15);
                    int d0 = ks * 32 + (lane >> 4) * 8;
                    kf[kvf] = *(const short8*)&Kt[cur][row * 64 + (d0 ^ ((row & 7) << 3))];
                }
#pragma unroll
                for (int kvf = 0; kvf < 4; kvf++)
#pragma unroll
                    for (int qf = 0; qf < 2; qf++)
                        st[kvf][qf] = __builtin_amdgcn_mfma_f32_16x16x32_bf16(kf[kvf], qfr[qf][ks], st[kvf][qf], 0, 0, 0);
            }
            __builtin_amdgcn_s_setprio(0);

            // ---- causal mask (diagonal-crossing tiles only)
            if ((kvbase + 63) > qw) {
#pragma unroll
                for (int qf = 0; qf < 2; qf++) {
                    const int q = qw + qf * 16 + (lane & 15);
#pragma unroll
                    for (int kvf = 0; kvf < 4; kvf++)
#pragma unroll
                        for (int r = 0; r < 4; r++) {
                            int kv = kvbase + kvf * 16 + (lane >> 4) * 4 + r;
                            if (kv > q) st[kvf][qf][r] = -1e30f;
                        }
                }
            }

            // ---- online softmax (base 2), defer-max, lane-partial l
#pragma unroll
            for (int qf = 0; qf < 2; qf++) {
                float tmax = st[0][qf][0];
#pragma unroll
                for (int kvf = 0; kvf < 4; kvf++)
#pragma unroll
                    for (int r = 0; r < 4; r++) tmax = fmaxf(tmax, st[kvf][qf][r]);
                tmax = fmaxf(tmax, __shfl_xor(tmax, 16, 64));
                tmax = fmaxf(tmax, __shfl_xor(tmax, 32, 64));
                const bool norescale = __all((int)(tmax <= m_run[qf] + 8.f));
                if (!norescale) {
                    const float mnew = fmaxf(m_run[qf], tmax);
                    const float sc = __builtin_exp2f(m_run[qf] - mnew);
                    m_run[qf] = mnew;
                    l_part[qf] *= sc;
#pragma unroll
                    for (int dkf = 0; dkf < 4; dkf++)
#pragma unroll
                        for (int r = 0; r < 4; r++) accT[dkf][qf][r] *= sc;
                }
                const float mq = m_run[qf];
                float ts = 0.f;
#pragma unroll
                for (int kvf = 0; kvf < 4; kvf++)
#pragma unroll
                    for (int r = 0; r < 4; r++) {
                        float p = __builtin_exp2f(st[kvf][qf][r] - mq);
                        st[kvf][qf][r] = p;
                        ts += p;
                    }
                l_part[qf] += ts;
                const int qrow = qf * 16 + (lane & 15);
#pragma unroll
                for (int kvf = 0; kvf < 4; kvf++) {
                    u32x2 pk;
                    pk[0] = pk2(st[kvf][qf][0], st[kvf][qf][1]);
                    pk[1] = pk2(st[kvf][qf][2], st[kvf][qf][3]);
                    int kvi = (kvf * 16 + (lane >> 4) * 4) ^ ((lane & 7) << 3);
                    *(u32x2*)&Pq[w][qrow * 64 + kvi] = pk;
                }
            }

            // ---- PV: ctx^T += V^T @ P^T
#pragma unroll
            for (int kf2 = 0; kf2 < 2; kf2++) {
                short8 vfr[4];
#pragma unroll
                for (int dkf = 0; dkf < 4; dkf++) {
                    int d = dkf * 16 + (lane & 15);
                    int kvi = (kf2 * 32 + (lane >> 4) * 8) ^ ((((d & 7) ^ (d >> 3)) & 7) << 3);
                    vfr[dkf] = *(const short8*)&Vt[cur][d * 64 + kvi];
                }
                short8 pfr[2];
#pragma unroll
                for (int qf = 0; qf < 2; qf++) {
                    int qrow = qf * 16 + (lane & 15);
                    int kvi = (kf2 * 32 + (lane >> 4) * 8) ^ ((lane & 7) << 3);
                    pfr[qf] = *(const short8*)&Pq[w][qrow * 64 + kvi];
                }
                __builtin_amdgcn_s_setprio(1);
#pragma unroll
                for (int dkf = 0; dkf < 4; dkf++)
#pragma unroll
                    for (int qf = 0; qf < 2; qf++)
                        accT[dkf][qf] = __builtin_amdgcn_mfma_f32_16x16x32_bf16(vfr[dkf], pfr[qf], accT[dkf][qf], 0, 0, 0);
                __builtin_amdgcn_s_setprio(0);
            }
        }

        // write staged V regs into the other buffer
        if (more) {
#pragma unroll
            for (int i = 0; i < 2; i++) {
                int kv = i * 32 + skv;
                const u16* pv = (const u16*)&vr[i];
#pragma unroll
                for (int j = 0; j < 8; j++) {
                    int d = sdb + j;
                    Vt[cur ^ 1][d * 64 + (kv ^ ((((d & 7) ^ (d >> 3)) & 7) << 3))] = pv[j];
                }
            }
        }
        __syncthreads();  // also drains K glds into buf^1
    }

    // ---- epilogue: reduce l across lane groups, divide, write bf16 [B,L,D]
    const int b = bh >> 4, h = bh & 15;
#pragma unroll
    for (int qf = 0; qf < 2; qf++) {
        float l = l_part[qf];
        l += __shfl_xor(l, 16, 64);
        l += __shfl_xor(l, 32, 64);
        const float inv = 1.f / l;
        const int q = qw + qf * 16 + (lane & 15);
#pragma unroll
        for (int dkf = 0; dkf < 4; dkf++) {
            const int dk0 = dkf * 16 + (lane >> 4) * 4;
            u32x2 o;
            o[0] = pk2(accT[dkf][qf][0] * inv, accT[dkf][qf][1] * inv);
            o[1] = pk2(accT[dkf][qf][2] * inv, accT[dkf][qf][3] * inv);
            long addr = ((long)b * Lseq + q) * Dm + h * Dk + dk0;
            *(u32x2*)(Ctx + addr) = o;
        }
    }
}

// ---------------------------------------------------------------------------
extern "C" void kernel_launch(void* const* d_in, const int* in_sizes, int n_in,
                              void* d_out, int out_size, void* d_ws, size_t ws_size,
                              hipStream_t stream)
{
    const float* query = (const float*)d_in[0];
    const float* key_  = (const float*)d_in[1];
    const float* value = (const float*)d_in[2];
    const float* Wq = (const float*)d_in[3];
    const float* bq = (const float*)d_in[4];
    const float* Wk = (const float*)d_in[5];
    const float* bk = (const float*)d_in[6];
    const float* Wv = (const float*)d_in[7];
    const float* bv = (const float*)d_in[8];
    const float* Wo = (const float*)d_in[9];
    const float* bo = (const float*)d_in[10];
    // d_in[11] = attn_mask (bool causal) — derived from indices instead.

    float* out = (float*)d_out;
    const size_t tens = (size_t)Bsz * Lseq * Dm;   // 8,388,608
    const size_t wTot = (size_t)Dm * Dm;           // 1,048,576
    u16* Qb = (u16*)d_ws;        // bf16 [B,H,L,DK], pre-scaled by 1/8*log2e
    u16* Kb = Qb + tens;
    u16* Vb = Kb + tens;

    dim3 g(64, 8), blk(256);
    const size_t need = (4 * tens + 4 * wTot) * sizeof(u16);  // 75.5 MB

    if (ws_size >= need) {
        // -------- fast path: pre-convert to bf16, glds GEMMs --------
        u16* Xb = Vb + tens;          // X staging, later aliased by Cx
        u16* Cx = Xb;
        u16* Wqb = Xb + tens;
        u16* Wkb = Wqb + wTot;
        u16* Wvb = Wkb + wTot;
        u16* Wob = Wvb + wTot;
        const int n8w = (int)(wTot / 8), n8x = (int)(tens / 8);
        const int gw = (n8w + 255) / 256, gx = (n8x + 255) / 256;
        cvt_f2b<<<gw, blk, 0, stream>>>(Wq, Wqb, n8w);
        cvt_f2b<<<gw, blk, 0, stream>>>(Wk, Wkb, n8w);
        cvt_f2b<<<gw, blk, 0, stream>>>(Wv, Wvb, n8w);
        cvt_f2b<<<gw, blk, 0, stream>>>(Wo, Wob, n8w);

        cvt_f2b<<<gx, blk, 0, stream>>>(query, Xb, n8x);
        gemm_glds<0><<<g, blk, 0, stream>>>(Xb, Wqb, bq, Qb, QSCALE);
        cvt_f2b<<<gx, blk, 0, stream>>>(key_, Xb, n8x);
        gemm_glds<0><<<g, blk, 0, stream>>>(Xb, Wkb, bk, Kb, 1.0f);
        cvt_f2b<<<gx, blk, 0, stream>>>(value, Xb, n8x);
        gemm_glds<0><<<g, blk, 0, stream>>>(Xb, Wvb, bv, Vb, 1.0f);

        attn_fwd<<<dim3(Bsz * Hn, Lseq / 128), blk, 0, stream>>>(Qb, Kb, Vb, Cx);
        gemm_glds<1><<<g, blk, 0, stream>>>(Cx, Wob, bo, out, 1.0f);
    } else {
        // -------- fallback (R4 proven): in-staging conversion --------
        u16* Cx = Vb + tens;
        gemm_bt<0, 1><<<g, blk, 0, stream>>>(query, Wq, bq, Qb, Dm, QSCALE);
        gemm_bt<0, 1><<<g, blk, 0, stream>>>(key_,  Wk, bk, Kb, Dm, 1.0f);
        gemm_bt<0, 1><<<g, blk, 0, stream>>>(value, Wv, bv, Vb, Dm, 1.0f);
        attn_fwd<<<dim3(Bsz * Hn, Lseq / 128), blk, 0, stream>>>(Qb, Kb, Vb, Cx);
        gemm_bt<1, 0><<<g, blk, 0, stream>>>(Cx, Wo, bo, out, Dm, 1.0f);
    }
}

// Round 7
// 243.634 us; speedup vs baseline: 1.4904x; 1.0334x over previous
//
#include <hip/hip_runtime.h>
#include <hip/hip_bf16.h>
#include <stdint.h>

typedef unsigned short u16;
typedef unsigned int u32;
typedef short short8 __attribute__((ext_vector_type(8)));
typedef float f32x4 __attribute__((ext_vector_type(4)));
typedef u32 u32x4 __attribute__((ext_vector_type(4)));
typedef u32 u32x2 __attribute__((ext_vector_type(2)));

#define DEV static __device__ __forceinline__

constexpr int Bsz = 4, Lseq = 2048, Dm = 1024, Hn = 16, Dk = 64;
constexpr float LOG2E = 1.44269504088896340736f;
constexpr float QSCALE = 0.125f * LOG2E;  // folded into Q projection

DEV u16 f2bf(float x) {
    u32 u = __builtin_bit_cast(u32, x);
    return (u16)((u + 0x7fffu + ((u >> 16) & 1u)) >> 16);
}

// pack 2 fp32 -> 2 bf16 in a u32 via HW v_cvt_pk_bf16_f32 path
DEV u32 pk2(float a, float b) {
    __hip_bfloat162 h = __float22bfloat162_rn(float2{a, b});
    u32 r;
    __builtin_memcpy(&r, &h, 4);
    return r;
}

// load 8 consecutive fp32, RNE to bf16, pack as u32x4
DEV u32x4 ld8_cvt(const float* p) {
    f32x4 lo = *(const f32x4*)p;
    f32x4 hi = *(const f32x4*)(p + 4);
    u32x4 r;
    r[0] = pk2(lo[0], lo[1]);
    r[1] = pk2(lo[2], lo[3]);
    r[2] = pk2(hi[0], hi[1]);
    r[3] = pk2(hi[2], hi[3]);
    return r;
}

// async global->LDS, 16B per lane; lds dest = wave-uniform base + lane*16
DEV void glds16(const void* g, void* l) {
    __builtin_amdgcn_global_load_lds(
        (const __attribute__((address_space(1))) void*)g,
        (__attribute__((address_space(3))) void*)l, 16, 0, 0);
}

// ---------------------------------------------------------------------------
// fp32 -> bf16 conversion, 8 elems/thread (proven R5)
// ---------------------------------------------------------------------------
__global__ __launch_bounds__(256) void cvt_f2b(
    const float* __restrict__ s, u16* __restrict__ d, int n8)
{
    int i = blockIdx.x * 256 + threadIdx.x;
    if (i >= n8) return;
    ((u32x4*)d)[i] = ld8_cvt(s + (long)i * 8);
}

// ---------------------------------------------------------------------------
// All-bf16 GEMM (R5-proven): C = (A[M,1024] @ W[N,1024]^T + bias) * scale
// global_load_lds w=16 both operands, 128x128 tile, BK=32, 4 waves (2x2).
// MODE 0: bf16 headed [B,H,L,DK] out;  MODE 1: fp32 row-major [M,N] out.
// ---------------------------------------------------------------------------
template <int MODE>
__global__ __launch_bounds__(256) void gemm_glds(
    const u16* __restrict__ A, const u16* __restrict__ Bw,
    const float* __restrict__ bias, void* __restrict__ Cout, float scale)
{
    __shared__ u16 At[2][128 * 32];
    __shared__ u16 Bt[2][128 * 32];

    const int tid = threadIdx.x;
    const int lane = tid & 63, wid = tid >> 6;
    const int wr = wid >> 1, wc = wid & 1;
    const int mbase = blockIdx.x * 128, nbase = blockIdx.y * 128;

    f32x4 acc[4][4];
#pragma unroll
    for (int i = 0; i < 4; i++)
#pragma unroll
        for (int j = 0; j < 4; j++) acc[i][j] = (f32x4)0.f;

    const int srow = lane >> 2;        // row within 16-row section
    const int sseg = (lane & 3) * 8;   // col element offset

    auto stage = [&](int kt, int buf) {
#pragma unroll
        for (int c = 0; c < 2; c++) {
            const int sec = wid * 2 + c;
            const long ko = (long)kt * 32 + sseg;
            glds16(A + (long)(mbase + sec * 16 + srow) * Dm + ko, &At[buf][sec * 512]);
            glds16(Bw + (long)(nbase + sec * 16 + srow) * Dm + ko, &Bt[buf][sec * 512]);
        }
    };

    stage(0, 0);
    __syncthreads();

    for (int kt = 0; kt < 32; kt++) {
        const int cur = kt & 1;
        if (kt + 1 < 32) stage(kt + 1, cur ^ 1);
        short8 af[4], bfr[4];
#pragma unroll
        for (int mf = 0; mf < 4; mf++)
            af[mf] = *(const short8*)&At[cur][(wr * 64 + mf * 16 + (lane & 15)) * 32 + (lane >> 4) * 8];
#pragma unroll
        for (int nf = 0; nf < 4; nf++)
            bfr[nf] = *(const short8*)&Bt[cur][(wc * 64 + nf * 16 + (lane & 15)) * 32 + (lane >> 4) * 8];
        __builtin_amdgcn_s_setprio(1);
#pragma unroll
        for (int mf = 0; mf < 4; mf++)
#pragma unroll
            for (int nf = 0; nf < 4; nf++)
                acc[mf][nf] = __builtin_amdgcn_mfma_f32_16x16x32_bf16(af[mf], bfr[nf], acc[mf][nf], 0, 0, 0);
        __builtin_amdgcn_s_setprio(0);
        __syncthreads();  // drains vmcnt -> next buffer ready
    }

#pragma unroll
    for (int nf = 0; nf < 4; nf++) {
        const int n = nbase + wc * 64 + nf * 16 + (lane & 15);
        const float bv = bias[n];
#pragma unroll
        for (int mf = 0; mf < 4; mf++) {
            const int m0 = mbase + wr * 64 + mf * 16 + (lane >> 4) * 4;
#pragma unroll
            for (int r = 0; r < 4; r++) {
                const int m = m0 + r;
                const float v = (acc[mf][nf][r] + bv) * scale;
                if (MODE == 0) {
                    int b = m >> 11, l = m & 2047, h = n >> 6, dk = n & 63;
                    long addr = ((long)(b * Hn + h) * Lseq + l) * Dk + dk;
                    ((u16*)Cout)[addr] = f2bf(v);
                } else {
                    ((float*)Cout)[(long)m * Dm + n] = v;
                }
            }
        }
    }
}

// ---------------------------------------------------------------------------
// Hybrid GEMM: A fp32 reg-staged with in-flight cvt (R4-proven A-side),
// B bf16 via global_load_lds w=16 (R5-proven B-side).
// C = (A[M,1024] @ W[N,1024]^T + bias) * scale, bf16 headed [B,H,L,DK] out.
// ---------------------------------------------------------------------------
__global__ __launch_bounds__(256) void gemm_hyb(
    const float* __restrict__ X, const u16* __restrict__ Bw,
    const float* __restrict__ bias, u16* __restrict__ Cout, float scale)
{
    __shared__ u16 At[2][128 * 32];
    __shared__ u16 Bt[2][128 * 32];

    const int tid = threadIdx.x;
    const int lane = tid & 63, wid = tid >> 6;
    const int wr = wid >> 1, wc = wid & 1;
    const int mbase = blockIdx.x * 128, nbase = blockIdx.y * 128;

    f32x4 acc[4][4];
#pragma unroll
    for (int i = 0; i < 4; i++)
#pragma unroll
        for (int j = 0; j < 4; j++) acc[i][j] = (f32x4)0.f;

    // B staging (R5 gemm_glds pattern, verbatim)
    const int srow = lane >> 2;
    const int sseg = (lane & 3) * 8;
    auto stageB = [&](int kt, int buf) {
#pragma unroll
        for (int c = 0; c < 2; c++) {
            const int sec = wid * 2 + c;
            glds16(Bw + (long)(nbase + sec * 16 + srow) * Dm + (long)kt * 32 + sseg,
                   &Bt[buf][sec * 512]);
        }
    };

    // A staging (R4 gemm_bt pattern, verbatim A-side)
    u32x4 va[2];
    auto loadA = [&](int kt) {
#pragma unroll
        for (int i = 0; i < 2; i++) {
            int idx = i * 256 + tid;
            int row = idx >> 2, seg = idx & 3;
            va[i] = ld8_cvt(X + (long)(mbase + row) * Dm + (long)kt * 32 + seg * 8);
        }
    };
    auto writeA = [&](int buf) {
#pragma unroll
        for (int i = 0; i < 2; i++) {
            int idx = i * 256 + tid;
            *(u32x4*)&At[buf][idx * 8] = va[i];
        }
    };

    stageB(0, 0);
    loadA(0);
    writeA(0);
    __syncthreads();

    for (int kt = 0; kt < 32; kt++) {
        const int cur = kt & 1;
        const bool more = (kt + 1 < 32);
        if (more) {
            stageB(kt + 1, cur ^ 1);
            loadA(kt + 1);
        }
        short8 af[4], bfr[4];
#pragma unroll
        for (int mf = 0; mf < 4; mf++)
            af[mf] = *(const short8*)&At[cur][(wr * 64 + mf * 16 + (lane & 15)) * 32 + (lane >> 4) * 8];
#pragma unroll
        for (int nf = 0; nf < 4; nf++)
            bfr[nf] = *(const short8*)&Bt[cur][(wc * 64 + nf * 16 + (lane & 15)) * 32 + (lane >> 4) * 8];
        __builtin_amdgcn_s_setprio(1);
#pragma unroll
        for (int mf = 0; mf < 4; mf++)
#pragma unroll
            for (int nf = 0; nf < 4; nf++)
                acc[mf][nf] = __builtin_amdgcn_mfma_f32_16x16x32_bf16(af[mf], bfr[nf], acc[mf][nf], 0, 0, 0);
        __builtin_amdgcn_s_setprio(0);
        if (more) writeA(cur ^ 1);
        __syncthreads();
    }

#pragma unroll
    for (int nf = 0; nf < 4; nf++) {
        const int n = nbase + wc * 64 + nf * 16 + (lane & 15);
        const float bv = bias[n];
#pragma unroll
        for (int mf = 0; mf < 4; mf++) {
            const int m0 = mbase + wr * 64 + mf * 16 + (lane >> 4) * 4;
#pragma unroll
            for (int r = 0; r < 4; r++) {
                const int m = m0 + r;
                const float v = (acc[mf][nf][r] + bv) * scale;
                int b = m >> 11, l = m & 2047, h = n >> 6, dk = n & 63;
                long addr = ((long)(b * Hn + h) * Lseq + l) * Dk + dk;
                Cout[addr] = f2bf(v);
            }
        }
    }
}

// ---------------------------------------------------------------------------
// Flash attention (R5-proven, verbatim). Causal, base-2 softmax (Q pre-scaled
// by 1/8*log2e). Grid: (B*H, L/128), qt reversed. Block 256 = 4 waves,
// wave w owns q rows [qt*128+w*32, +32). Double-buffered K/V, 1 barrier/iter.
// K: glds w=16 with pre-swizzled source; read col ^ ((kv&7)<<3).
// V: reg transpose-staged Vt[d][kv ^ (((d&7)^(d>>3))<<3)].
// P per-wave [32q][64kv], col ^ ((q&7)<<3). Defer-max (THR=8) +
// lane-partial l. setprio around MFMA clusters.
// ---------------------------------------------------------------------------
__global__ __launch_bounds__(256) void attn_fwd(
    const u16* __restrict__ Qb, const u16* __restrict__ Kb,
    const u16* __restrict__ Vb, u16* __restrict__ Ctx)
{
    __shared__ u16 Kt[2][64 * 64];
    __shared__ u16 Vt[2][64 * 64];
    __shared__ u16 Pq[4][32 * 64];

    const int tid = threadIdx.x, lane = tid & 63, w = tid >> 6;
    const int qt = gridDim.y - 1 - blockIdx.y;  // heavy-first
    const int bh = blockIdx.x;
    const long base = (long)bh * Lseq * Dk;
    const int qw = qt * 128 + w * 32;

    const int krow_in_w = lane >> 3;
    const int kseg = lane & 7;
    const int skv = tid >> 3, sdb = (tid & 7) * 8;

    auto stage_k = [&](int kvbase, int buf) {
#pragma unroll
        for (int c = 0; c < 2; c++) {
            int kv = w * 16 + c * 8 + krow_in_w;
            int d0 = ((kseg ^ (kv & 7)) * 8);
            glds16(Kb + base + (long)(kvbase + kv) * Dk + d0,
                   &Kt[buf][(w * 16 + c * 8) * 64]);
        }
    };

    // Q fragments in registers (log2 domain)
    short8 qfr[2][2];
#pragma unroll
    for (int qf = 0; qf < 2; qf++)
#pragma unroll
        for (int ks = 0; ks < 2; ks++) {
            int q = qw + qf * 16 + (lane & 15);
            int d0 = ks * 32 + (lane >> 4) * 8;
            qfr[qf][ks] = *(const short8*)(Qb + base + (long)q * Dk + d0);
        }

    f32x4 accT[4][2];  // ctx^T: [dkf][qf]
#pragma unroll
    for (int i = 0; i < 4; i++)
#pragma unroll
        for (int j = 0; j < 2; j++) accT[i][j] = (f32x4)0.f;
    float m_run[2] = {-__builtin_inff(), -__builtin_inff()};
    float l_part[2] = {0.f, 0.f};

    u32x4 vr[2];
    stage_k(0, 0);
#pragma unroll
    for (int i = 0; i < 2; i++)
        vr[i] = *(const u32x4*)(Vb + base + (long)(i * 32 + skv) * Dk + sdb);
#pragma unroll
    for (int i = 0; i < 2; i++) {
        int kv = i * 32 + skv;
        const u16* pv = (const u16*)&vr[i];
#pragma unroll
        for (int j = 0; j < 8; j++) {
            int d = sdb + j;
            Vt[0][d * 64 + (kv ^ ((((d & 7) ^ (d >> 3)) & 7) << 3))] = pv[j];
        }
    }
    __syncthreads();

    const int nkv = qt * 2 + 2;
    const int myn = ((qw + 31) >> 6) + 1;  // tiles this wave computes

    for (int kvt = 0; kvt < nkv; kvt++) {
        const int cur = kvt & 1;
        const bool more = (kvt + 1 < nkv);
        const int kvbase = kvt * 64;

        if (more) {
            stage_k(kvbase + 64, cur ^ 1);
#pragma unroll
            for (int i = 0; i < 2; i++)
                vr[i] = *(const u32x4*)(Vb + base + (long)(kvbase + 64 + i * 32 + skv) * Dk + sdb);
        }

        if (kvt < myn) {
            // ---- S^T = K @ Q^T
            f32x4 st[4][2];
#pragma unroll
            for (int i = 0; i < 4; i++)
#pragma unroll
                for (int j = 0; j < 2; j++) st[i][j] = (f32x4)0.f;
            __builtin_amdgcn_s_setprio(1);
#pragma unroll
            for (int ks = 0; ks < 2; ks++) {
                short8 kf[4];
#pragma unroll
                for (int kvf = 0; kvf < 4; kvf++) {
                    int row = kvf * 16 + (lane & 15);
                    int d0 = ks * 32 + (lane >> 4) * 8;
                    kf[kvf] = *(const short8*)&Kt[cur][row * 64 + (d0 ^ ((row & 7) << 3))];
                }
#pragma unroll
                for (int kvf = 0; kvf < 4; kvf++)
#pragma unroll
                    for (int qf = 0; qf < 2; qf++)
                        st[kvf][qf] = __builtin_amdgcn_mfma_f32_16x16x32_bf16(kf[kvf], qfr[qf][ks], st[kvf][qf], 0, 0, 0);
            }
            __builtin_amdgcn_s_setprio(0);

            // ---- causal mask (diagonal tiles only)
            if ((kvbase + 63) > qw) {
#pragma unroll
                for (int qf = 0; qf < 2; qf++) {
                    const int q = qw + qf * 16 + (lane & 15);
#pragma unroll
                    for (int kvf = 0; kvf < 4; kvf++)
#pragma unroll
                        for (int r = 0; r < 4; r++) {
                            int kv = kvbase + kvf * 16 + (lane >> 4) * 4 + r;
                            if (kv > q) st[kvf][qf][r] = -1e30f;
                        }
                }
            }

            // ---- online softmax (base 2), defer-max, lane-partial l
#pragma unroll
            for (int qf = 0; qf < 2; qf++) {
                float tmax = st[0][qf][0];
#pragma unroll
                for (int kvf = 0; kvf < 4; kvf++)
#pragma unroll
                    for (int r = 0; r < 4; r++) tmax = fmaxf(tmax, st[kvf][qf][r]);
                tmax = fmaxf(tmax, __shfl_xor(tmax, 16, 64));
                tmax = fmaxf(tmax, __shfl_xor(tmax, 32, 64));
                const bool norescale = __all((int)(tmax <= m_run[qf] + 8.f));
                if (!norescale) {
                    const float mnew = fmaxf(m_run[qf], tmax);
                    const float sc = __builtin_exp2f(m_run[qf] - mnew);
                    m_run[qf] = mnew;
                    l_part[qf] *= sc;
#pragma unroll
                    for (int dkf = 0; dkf < 4; dkf++)
#pragma unroll
                        for (int r = 0; r < 4; r++) accT[dkf][qf][r] *= sc;
                }
                const float mq = m_run[qf];
                float ts = 0.f;
#pragma unroll
                for (int kvf = 0; kvf < 4; kvf++)
#pragma unroll
                    for (int r = 0; r < 4; r++) {
                        float p = __builtin_exp2f(st[kvf][qf][r] - mq);
                        st[kvf][qf][r] = p;
                        ts += p;
                    }
                l_part[qf] += ts;
                const int qrow = qf * 16 + (lane & 15);
#pragma unroll
                for (int kvf = 0; kvf < 4; kvf++) {
                    u32x2 pk;
                    pk[0] = pk2(st[kvf][qf][0], st[kvf][qf][1]);
                    pk[1] = pk2(st[kvf][qf][2], st[kvf][qf][3]);
                    int kvi = (kvf * 16 + (lane >> 4) * 4) ^ ((lane & 7) << 3);
                    *(u32x2*)&Pq[w][qrow * 64 + kvi] = pk;
                }
            }

            // ---- PV: ctx^T += V^T @ P^T
#pragma unroll
            for (int kf2 = 0; kf2 < 2; kf2++) {
                short8 vfr[4];
#pragma unroll
                for (int dkf = 0; dkf < 4; dkf++) {
                    int d = dkf * 16 + (lane & 15);
                    int kvi = (kf2 * 32 + (lane >> 4) * 8) ^ ((((d & 7) ^ (d >> 3)) & 7) << 3);
                    vfr[dkf] = *(const short8*)&Vt[cur][d * 64 + kvi];
                }
                short8 pfr[2];
#pragma unroll
                for (int qf = 0; qf < 2; qf++) {
                    int qrow = qf * 16 + (lane & 15);
                    int kvi = (kf2 * 32 + (lane >> 4) * 8) ^ ((lane & 7) << 3);
                    pfr[qf] = *(const short8*)&Pq[w][qrow * 64 + kvi];
                }
                __builtin_amdgcn_s_setprio(1);
#pragma unroll
                for (int dkf = 0; dkf < 4; dkf++)
#pragma unroll
                    for (int qf = 0; qf < 2; qf++)
                        accT[dkf][qf] = __builtin_amdgcn_mfma_f32_16x16x32_bf16(vfr[dkf], pfr[qf], accT[dkf][qf], 0, 0, 0);
                __builtin_amdgcn_s_setprio(0);
            }
        }

        // write staged V regs into the other buffer
        if (more) {
#pragma unroll
            for (int i = 0; i < 2; i++) {
                int kv = i * 32 + skv;
                const u16* pv = (const u16*)&vr[i];
#pragma unroll
                for (int j = 0; j < 8; j++) {
                    int d = sdb + j;
                    Vt[cur ^ 1][d * 64 + (kv ^ ((((d & 7) ^ (d >> 3)) & 7) << 3))] = pv[j];
                }
            }
        }
        __syncthreads();  // drains glds (vmcnt) for buf^1
    }

    // ---- epilogue: reduce l, divide, write bf16 [B,L,D]
    const int b = bh >> 4, h = bh & 15;
#pragma unroll
    for (int qf = 0; qf < 2; qf++) {
        float l = l_part[qf];
        l += __shfl_xor(l, 16, 64);
        l += __shfl_xor(l, 32, 64);
        const float inv = 1.f / l;
        const int q = qw + qf * 16 + (lane & 15);
#pragma unroll
        for (int dkf = 0; dkf < 4; dkf++) {
            const int dk0 = dkf * 16 + (lane >> 4) * 4;
            u32x2 o;
            o[0] = pk2(accT[dkf][qf][0] * inv, accT[dkf][qf][1] * inv);
            o[1] = pk2(accT[dkf][qf][2] * inv, accT[dkf][qf][3] * inv);
            long addr = ((long)b * Lseq + q) * Dm + h * Dk + dk0;
            *(u32x2*)(Ctx + addr) = o;
        }
    }
}

// ---------------------------------------------------------------------------
extern "C" void kernel_launch(void* const* d_in, const int* in_sizes, int n_in,
                              void* d_out, int out_size, void* d_ws, size_t ws_size,
                              hipStream_t stream)
{
    const float* query = (const float*)d_in[0];
    const float* key_  = (const float*)d_in[1];
    const float* value = (const float*)d_in[2];
    const float* Wq = (const float*)d_in[3];
    const float* bq = (const float*)d_in[4];
    const float* Wk = (const float*)d_in[5];
    const float* bk = (const float*)d_in[6];
    const float* Wv = (const float*)d_in[7];
    const float* bv = (const float*)d_in[8];
    const float* Wo = (const float*)d_in[9];
    const float* bo = (const float*)d_in[10];
    // d_in[11] = attn_mask (bool causal) — derived from indices instead.

    float* out = (float*)d_out;
    const size_t tens = (size_t)Bsz * Lseq * Dm;   // 8,388,608
    const size_t wTot = (size_t)Dm * Dm;           // 1,048,576
    // ws layout (4*tens*2B = 67.1 MB, proven available):
    u16* Qb = (u16*)d_ws;        // bf16 [B,H,L,DK] (Q pre-scaled)
    u16* Kb = Qb + tens;
    u16* Vb = Kb + tens;
    u16* Cx = Vb + tens;         // attn output [B,L,D]
    // weight bf16 buffers alias dead regions:
    u16* Wqb = Cx;               // Wq/Wk/Wv live in Cx slot until attn
    u16* Wkb = Wqb + wTot;
    u16* Wvb = Wkb + wTot;
    u16* Wob = Qb;               // converted AFTER attn (Qb dead by then)

    dim3 blk(256), g(64, 8);
    const int n8w = (int)(wTot / 8);
    const int gw = (n8w + 255) / 256;

    cvt_f2b<<<gw, blk, 0, stream>>>(Wq, Wqb, n8w);
    cvt_f2b<<<gw, blk, 0, stream>>>(Wk, Wkb, n8w);
    cvt_f2b<<<gw, blk, 0, stream>>>(Wv, Wvb, n8w);
    gemm_hyb<<<g, blk, 0, stream>>>(query, Wqb, bq, Qb, QSCALE);
    gemm_hyb<<<g, blk, 0, stream>>>(key_,  Wkb, bk, Kb, 1.0f);
    gemm_hyb<<<g, blk, 0, stream>>>(value, Wvb, bv, Vb, 1.0f);
    attn_fwd<<<dim3(Bsz * Hn, Lseq / 128), blk, 0, stream>>>(Qb, Kb, Vb, Cx);
    cvt_f2b<<<gw, blk, 0, stream>>>(Wo, Wob, n8w);
    gemm_glds<1><<<g, blk, 0, stream>>>(Cx, Wob, bo, out, 1.0f);
}

// Round 9
// 223.772 us; speedup vs baseline: 1.6227x; 1.0888x over previous
//
#include <hip/hip_runtime.h>
#include <hip/hip_bf16.h>
#include <stdint.h>

typedef unsigned short u16;
typedef unsigned int u32;
typedef short short8 __attribute__((ext_vector_type(8)));
typedef float f32x4 __attribute__((ext_vector_type(4)));
typedef u32 u32x4 __attribute__((ext_vector_type(4)));
typedef u32 u32x2 __attribute__((ext_vector_type(2)));

#define DEV static __device__ __forceinline__

constexpr int Bsz = 4, Lseq = 2048, Dm = 1024, Hn = 16, Dk = 64;
constexpr float LOG2E = 1.44269504088896340736f;
constexpr float QSCALE = 0.125f * LOG2E;  // folded into Q projection

DEV u16 f2bf(float x) {
    u32 u = __builtin_bit_cast(u32, x);
    return (u16)((u + 0x7fffu + ((u >> 16) & 1u)) >> 16);
}

// pack 2 fp32 -> 2 bf16 in a u32 via HW v_cvt_pk_bf16_f32 path
DEV u32 pk2(float a, float b) {
    __hip_bfloat162 h = __float22bfloat162_rn(float2{a, b});
    u32 r;
    __builtin_memcpy(&r, &h, 4);
    return r;
}

// load 8 consecutive fp32, RNE to bf16, pack as u32x4
DEV u32x4 ld8_cvt(const float* p) {
    f32x4 lo = *(const f32x4*)p;
    f32x4 hi = *(const f32x4*)(p + 4);
    u32x4 r;
    r[0] = pk2(lo[0], lo[1]);
    r[1] = pk2(lo[2], lo[3]);
    r[2] = pk2(hi[0], hi[1]);
    r[3] = pk2(hi[2], hi[3]);
    return r;
}

// async global->LDS, 16B per lane; lds dest = wave-uniform base + lane*16
DEV void glds16(const void* g, void* l) {
    __builtin_amdgcn_global_load_lds(
        (const __attribute__((address_space(1))) void*)g,
        (__attribute__((address_space(3))) void*)l, 16, 0, 0);
}

// ---------------------------------------------------------------------------
// fp32 -> bf16 conversion, 8 elems/thread (proven R5)
// ---------------------------------------------------------------------------
__global__ __launch_bounds__(256) void cvt_f2b(
    const float* __restrict__ s, u16* __restrict__ d, int n8)
{
    int i = blockIdx.x * 256 + threadIdx.x;
    if (i >= n8) return;
    ((u32x4*)d)[i] = ld8_cvt(s + (long)i * 8);
}

// ---------------------------------------------------------------------------
// All-bf16 GEMM (R5-proven): C = (A[M,1024] @ W[N,1024]^T + bias) * scale
// global_load_lds w=16 both operands, 128x128 tile, BK=32, 4 waves (2x2).
// fp32 row-major [M,N] out (final projection).
// ---------------------------------------------------------------------------
__global__ __launch_bounds__(256) void gemm_glds(
    const u16* __restrict__ A, const u16* __restrict__ Bw,
    const float* __restrict__ bias, float* __restrict__ Cout, float scale)
{
    __shared__ u16 At[2][128 * 32];
    __shared__ u16 Bt[2][128 * 32];

    const int tid = threadIdx.x;
    const int lane = tid & 63, wid = tid >> 6;
    const int wr = wid >> 1, wc = wid & 1;
    const int mbase = blockIdx.x * 128, nbase = blockIdx.y * 128;

    f32x4 acc[4][4];
#pragma unroll
    for (int i = 0; i < 4; i++)
#pragma unroll
        for (int j = 0; j < 4; j++) acc[i][j] = (f32x4)0.f;

    const int srow = lane >> 2;
    const int sseg = (lane & 3) * 8;

    auto stage = [&](int kt, int buf) {
#pragma unroll
        for (int c = 0; c < 2; c++) {
            const int sec = wid * 2 + c;
            const long ko = (long)kt * 32 + sseg;
            glds16(A + (long)(mbase + sec * 16 + srow) * Dm + ko, &At[buf][sec * 512]);
            glds16(Bw + (long)(nbase + sec * 16 + srow) * Dm + ko, &Bt[buf][sec * 512]);
        }
    };

    stage(0, 0);
    __syncthreads();

    for (int kt = 0; kt < 32; kt++) {
        const int cur = kt & 1;
        if (kt + 1 < 32) stage(kt + 1, cur ^ 1);
        short8 af[4], bfr[4];
#pragma unroll
        for (int mf = 0; mf < 4; mf++)
            af[mf] = *(const short8*)&At[cur][(wr * 64 + mf * 16 + (lane & 15)) * 32 + (lane >> 4) * 8];
#pragma unroll
        for (int nf = 0; nf < 4; nf++)
            bfr[nf] = *(const short8*)&Bt[cur][(wc * 64 + nf * 16 + (lane & 15)) * 32 + (lane >> 4) * 8];
        __builtin_amdgcn_s_setprio(1);
#pragma unroll
        for (int mf = 0; mf < 4; mf++)
#pragma unroll
            for (int nf = 0; nf < 4; nf++)
                acc[mf][nf] = __builtin_amdgcn_mfma_f32_16x16x32_bf16(af[mf], bfr[nf], acc[mf][nf], 0, 0, 0);
        __builtin_amdgcn_s_setprio(0);
        __syncthreads();
    }

#pragma unroll
    for (int nf = 0; nf < 4; nf++) {
        const int n = nbase + wc * 64 + nf * 16 + (lane & 15);
        const float bv = bias[n];
#pragma unroll
        for (int mf = 0; mf < 4; mf++) {
            const int m0 = mbase + wr * 64 + mf * 16 + (lane >> 4) * 4;
#pragma unroll
            for (int r = 0; r < 4; r++) {
                const int m = m0 + r;
                Cout[(long)m * Dm + n] = (acc[mf][nf][r] + bv) * scale;
            }
        }
    }
}

// ---------------------------------------------------------------------------
// Fused QKV GEMM: one dispatch computes all three projections.
// Grid (64, 24): t = blockIdx.y>>3 selects {X input, W slab, bias, scale,
// output} — ALL block-uniform. Body = R7-proven gemm_hyb verbatim:
// A fp32 reg-staged with in-flight cvt; B bf16 via glds w=16.
// Out: bf16 headed [B,H,L,DK].
// ---------------------------------------------------------------------------
__global__ __launch_bounds__(256) void gemm_qkv(
    const float* __restrict__ Xq, const float* __restrict__ Xk,
    const float* __restrict__ Xv, const u16* __restrict__ Wb3,
    const float* __restrict__ bq, const float* __restrict__ bk,
    const float* __restrict__ bv, u16* __restrict__ Out3)
{
    __shared__ u16 At[2][128 * 32];
    __shared__ u16 Bt[2][128 * 32];

    const int tid = threadIdx.x;
    const int lane = tid & 63, wid = tid >> 6;
    const int wr = wid >> 1, wc = wid & 1;
    const int mbase = blockIdx.x * 128;
    const int t = blockIdx.y >> 3;              // 0:Q 1:K 2:V (block-uniform)
    const int nbase = (blockIdx.y & 7) * 128;
    const float* X = t == 0 ? Xq : (t == 1 ? Xk : Xv);
    const u16* Bw = Wb3 + (size_t)t * Dm * Dm;
    const float* bias = t == 0 ? bq : (t == 1 ? bk : bv);
    const float scale = t == 0 ? QSCALE : 1.0f;
    u16* Cout = Out3 + (size_t)t * ((size_t)Bsz * Lseq * Dm);

    f32x4 acc[4][4];
#pragma unroll
    for (int i = 0; i < 4; i++)
#pragma unroll
        for (int j = 0; j < 4; j++) acc[i][j] = (f32x4)0.f;

    // B staging (glds, R5/R7-proven)
    const int srow = lane >> 2;
    const int sseg = (lane & 3) * 8;
    auto stageB = [&](int kt, int buf) {
#pragma unroll
        for (int c = 0; c < 2; c++) {
            const int sec = wid * 2 + c;
            glds16(Bw + (long)(nbase + sec * 16 + srow) * Dm + (long)kt * 32 + sseg,
                   &Bt[buf][sec * 512]);
        }
    };

    // A staging (reg + in-flight cvt, R4/R7-proven)
    u32x4 va[2];
    auto loadA = [&](int kt) {
#pragma unroll
        for (int i = 0; i < 2; i++) {
            int idx = i * 256 + tid;
            int row = idx >> 2, seg = idx & 3;
            va[i] = ld8_cvt(X + (long)(mbase + row) * Dm + (long)kt * 32 + seg * 8);
        }
    };
    auto writeA = [&](int buf) {
#pragma unroll
        for (int i = 0; i < 2; i++) {
            int idx = i * 256 + tid;
            *(u32x4*)&At[buf][idx * 8] = va[i];
        }
    };

    stageB(0, 0);
    loadA(0);
    writeA(0);
    __syncthreads();

    for (int kt = 0; kt < 32; kt++) {
        const int cur = kt & 1;
        const bool more = (kt + 1 < 32);
        if (more) {
            stageB(kt + 1, cur ^ 1);
            loadA(kt + 1);
        }
        short8 af[4], bfr[4];
#pragma unroll
        for (int mf = 0; mf < 4; mf++)
            af[mf] = *(const short8*)&At[cur][(wr * 64 + mf * 16 + (lane & 15)) * 32 + (lane >> 4) * 8];
#pragma unroll
        for (int nf = 0; nf < 4; nf++)
            bfr[nf] = *(const short8*)&Bt[cur][(wc * 64 + nf * 16 + (lane & 15)) * 32 + (lane >> 4) * 8];
        __builtin_amdgcn_s_setprio(1);
#pragma unroll
        for (int mf = 0; mf < 4; mf++)
#pragma unroll
            for (int nf = 0; nf < 4; nf++)
                acc[mf][nf] = __builtin_amdgcn_mfma_f32_16x16x32_bf16(af[mf], bfr[nf], acc[mf][nf], 0, 0, 0);
        __builtin_amdgcn_s_setprio(0);
        if (more) writeA(cur ^ 1);
        __syncthreads();
    }

#pragma unroll
    for (int nf = 0; nf < 4; nf++) {
        const int n = nbase + wc * 64 + nf * 16 + (lane & 15);
        const float bv = bias[n];
#pragma unroll
        for (int mf = 0; mf < 4; mf++) {
            const int m0 = mbase + wr * 64 + mf * 16 + (lane >> 4) * 4;
#pragma unroll
            for (int r = 0; r < 4; r++) {
                const int m = m0 + r;
                const float v = (acc[mf][nf][r] + bv) * scale;
                int b = m >> 11, l = m & 2047, h = n >> 6, dk = n & 63;
                long addr = ((long)(b * Hn + h) * Lseq + l) * Dk + dk;
                Cout[addr] = f2bf(v);
            }
        }
    }
}

// ---------------------------------------------------------------------------
// Flash attention (R5-proven structure). Causal, base-2 softmax (Q pre-scaled
// by 1/8*log2e). Grid: (B*H, L/128), qt reversed. Block 256 = 4 waves,
// wave w owns q rows [qt*128+w*32, +32). Double-buffered K/V, 1 barrier/iter.
// K: glds w=16 with pre-swizzled source; read col ^ ((kv&7)<<3).
// V: reg transpose-staged Vt[d][kv ^ (((d&7)^(d>>3))<<3)].
// P: per-wave [32q][32kv] (8 KB) TIME-SHARED across the two kf2 PV phases —
//    LDS 48->40 KB lifts occupancy. Swizzle: granule ^ (q&7) on 4-col
//    granules (b64 writes & b64-pair reads both aligned; bijective per row).
// Defer-max (THR=8) + lane-partial l. setprio around MFMA clusters.
// ---------------------------------------------------------------------------
__global__ __launch_bounds__(256) void attn_fwd(
    const u16* __restrict__ Qb, const u16* __restrict__ Kb,
    const u16* __restrict__ Vb, u16* __restrict__ Ctx)
{
    __shared__ u16 Kt[2][64 * 64];
    __shared__ u16 Vt[2][64 * 64];
    __shared__ u16 Pq[4][32 * 32];

    const int tid = threadIdx.x, lane = tid & 63, w = tid >> 6;
    const int qt = gridDim.y - 1 - blockIdx.y;  // heavy-first
    const int bh = blockIdx.x;
    const long base = (long)bh * Lseq * Dk;
    const int qw = qt * 128 + w * 32;

    const int krow_in_w = lane >> 3;
    const int kseg = lane & 7;
    const int skv = tid >> 3, sdb = (tid & 7) * 8;

    auto stage_k = [&](int kvbase, int buf) {
#pragma unroll
        for (int c = 0; c < 2; c++) {
            int kv = w * 16 + c * 8 + krow_in_w;
            int d0 = ((kseg ^ (kv & 7)) * 8);
            glds16(Kb + base + (long)(kvbase + kv) * Dk + d0,
                   &Kt[buf][(w * 16 + c * 8) * 64]);
        }
    };

    // Q fragments in registers (log2 domain)
    short8 qfr[2][2];
#pragma unroll
    for (int qf = 0; qf < 2; qf++)
#pragma unroll
        for (int ks = 0; ks < 2; ks++) {
            int q = qw + qf * 16 + (lane & 15);
            int d0 = ks * 32 + (lane >> 4) * 8;
            qfr[qf][ks] = *(const short8*)(Qb + base + (long)q * Dk + d0);
        }

    f32x4 accT[4][2];  // ctx^T: [dkf][qf]
#pragma unroll
    for (int i = 0; i < 4; i++)
#pragma unroll
        for (int j = 0; j < 2; j++) accT[i][j] = (f32x4)0.f;
    float m_run[2] = {-__builtin_inff(), -__builtin_inff()};
    float l_part[2] = {0.f, 0.f};

    u32x4 vr[2];
    stage_k(0, 0);
#pragma unroll
    for (int i = 0; i < 2; i++)
        vr[i] = *(const u32x4*)(Vb + base + (long)(i * 32 + skv) * Dk + sdb);
#pragma unroll
    for (int i = 0; i < 2; i++) {
        int kv = i * 32 + skv;
        const u16* pv = (const u16*)&vr[i];
#pragma unroll
        for (int j = 0; j < 8; j++) {
            int d = sdb + j;
            Vt[0][d * 64 + (kv ^ ((((d & 7) ^ (d >> 3)) & 7) << 3))] = pv[j];
        }
    }
    __syncthreads();

    const int nkv = qt * 2 + 2;
    const int myn = ((qw + 31) >> 6) + 1;  // tiles this wave computes

    for (int kvt = 0; kvt < nkv; kvt++) {
        const int cur = kvt & 1;
        const bool more = (kvt + 1 < nkv);
        const int kvbase = kvt * 64;

        if (more) {
            stage_k(kvbase + 64, cur ^ 1);
#pragma unroll
            for (int i = 0; i < 2; i++)
                vr[i] = *(const u32x4*)(Vb + base + (long)(kvbase + 64 + i * 32 + skv) * Dk + sdb);
        }

        if (kvt < myn) {
            // ---- S^T = K @ Q^T
            f32x4 st[4][2];
#pragma unroll
            for (int i = 0; i < 4; i++)
#pragma unroll
                for (int j = 0; j < 2; j++) st[i][j] = (f32x4)0.f;
            __builtin_amdgcn_s_setprio(1);
#pragma unroll
            for (int ks = 0; ks < 2; ks++) {
                short8 kf[4];
#pragma unroll
                for (int kvf = 0; kvf < 4; kvf++) {
                    int row = kvf * 16 + (lane & 15);
                    int d0 = ks * 32 + (lane >> 4) * 8;
                    kf[kvf] = *(const short8*)&Kt[cur][row * 64 + (d0 ^ ((row & 7) << 3))];
                }
#pragma unroll
                for (int kvf = 0; kvf < 4; kvf++)
#pragma unroll
                    for (int qf = 0; qf < 2; qf++)
                        st[kvf][qf] = __builtin_amdgcn_mfma_f32_16x16x32_bf16(kf[kvf], qfr[qf][ks], st[kvf][qf], 0, 0, 0);
            }
            __builtin_amdgcn_s_setprio(0);

            // ---- causal mask (diagonal tiles only)
            if ((kvbase + 63) > qw) {
#pragma unroll
                for (int qf = 0; qf < 2; qf++) {
                    const int q = qw + qf * 16 + (lane & 15);
#pragma unroll
                    for (int kvf = 0; kvf < 4; kvf++)
#pragma unroll
                        for (int r = 0; r < 4; r++) {
                            int kv = kvbase + kvf * 16 + (lane >> 4) * 4 + r;
                            if (kv > q) st[kvf][qf][r] = -1e30f;
                        }
                }
            }

            // ---- online softmax (base 2), defer-max, lane-partial l
#pragma unroll
            for (int qf = 0; qf < 2; qf++) {
                float tmax = st[0][qf][0];
#pragma unroll
                for (int kvf = 0; kvf < 4; kvf++)
#pragma unroll
                    for (int r = 0; r < 4; r++) tmax = fmaxf(tmax, st[kvf][qf][r]);
                tmax = fmaxf(tmax, __shfl_xor(tmax, 16, 64));
                tmax = fmaxf(tmax, __shfl_xor(tmax, 32, 64));
                const bool norescale = __all((int)(tmax <= m_run[qf] + 8.f));
                if (!norescale) {
                    const float mnew = fmaxf(m_run[qf], tmax);
                    const float sc = __builtin_exp2f(m_run[qf] - mnew);
                    m_run[qf] = mnew;
                    l_part[qf] *= sc;
#pragma unroll
                    for (int dkf = 0; dkf < 4; dkf++)
#pragma unroll
                        for (int r = 0; r < 4; r++) accT[dkf][qf][r] *= sc;
                }
                const float mq = m_run[qf];
                float ts = 0.f;
#pragma unroll
                for (int kvf = 0; kvf < 4; kvf++)
#pragma unroll
                    for (int r = 0; r < 4; r++) {
                        float p = __builtin_exp2f(st[kvf][qf][r] - mq);
                        st[kvf][qf][r] = p;
                        ts += p;
                    }
                l_part[qf] += ts;
            }

            // ---- PV: ctx^T += V^T @ P^T  (P staged per 32-kv half, 8KB)
#pragma unroll
            for (int kf2 = 0; kf2 < 2; kf2++) {
                // write this half of P (local kv 0..31)
#pragma unroll
                for (int qf = 0; qf < 2; qf++) {
                    const int qrow = qf * 16 + (lane & 15);
#pragma unroll
                    for (int k2 = 0; k2 < 2; k2++) {
                        const int kvf = kf2 * 2 + k2;
                        u32x2 pk;
                        pk[0] = pk2(st[kvf][qf][0], st[kvf][qf][1]);
                        pk[1] = pk2(st[kvf][qf][2], st[kvf][qf][3]);
                        const int kvi = (k2 * 16 + (lane >> 4) * 4) ^ ((lane & 7) << 2);
                        *(u32x2*)&Pq[w][qrow * 32 + kvi] = pk;
                    }
                }
                short8 vfr[4];
#pragma unroll
                for (int dkf = 0; dkf < 4; dkf++) {
                    int d = dkf * 16 + (lane & 15);
                    int kvi = (kf2 * 32 + (lane >> 4) * 8) ^ ((((d & 7) ^ (d >> 3)) & 7) << 3);
                    vfr[dkf] = *(const short8*)&Vt[cur][d * 64 + kvi];
                }
                short8 pfr[2];
#pragma unroll
                for (int qf = 0; qf < 2; qf++) {
                    const int qrow = qf * 16 + (lane & 15);
                    u32x2 lohi[2];
#pragma unroll
                    for (int h = 0; h < 2; h++) {
                        const int kvi = ((lane >> 4) * 8 + h * 4) ^ ((lane & 7) << 2);
                        lohi[h] = *(const u32x2*)&Pq[w][qrow * 32 + kvi];
                    }
                    __builtin_memcpy(&pfr[qf], lohi, 16);
                }
                __builtin_amdgcn_s_setprio(1);
#pragma unroll
                for (int dkf = 0; dkf < 4; dkf++)
#pragma unroll
                    for (int qf = 0; qf < 2; qf++)
                        accT[dkf][qf] = __builtin_amdgcn_mfma_f32_16x16x32_bf16(vfr[dkf], pfr[qf], accT[dkf][qf], 0, 0, 0);
                __builtin_amdgcn_s_setprio(0);
            }
        }

        // write staged V regs into the other buffer
        if (more) {
#pragma unroll
            for (int i = 0; i < 2; i++) {
                int kv = i * 32 + skv;
                const u16* pv = (const u16*)&vr[i];
#pragma unroll
                for (int j = 0; j < 8; j++) {
                    int d = sdb + j;
                    Vt[cur ^ 1][d * 64 + (kv ^ ((((d & 7) ^ (d >> 3)) & 7) << 3))] = pv[j];
                }
            }
        }
        __syncthreads();  // drains glds (vmcnt) for buf^1
    }

    // ---- epilogue: reduce l, divide, write bf16 [B,L,D]
    const int b = bh >> 4, h = bh & 15;
#pragma unroll
    for (int qf = 0; qf < 2; qf++) {
        float l = l_part[qf];
        l += __shfl_xor(l, 16, 64);
        l += __shfl_xor(l, 32, 64);
        const float inv = 1.f / l;
        const int q = qw + qf * 16 + (lane & 15);
#pragma unroll
        for (int dkf = 0; dkf < 4; dkf++) {
            const int dk0 = dkf * 16 + (lane >> 4) * 4;
            u32x2 o;
            o[0] = pk2(accT[dkf][qf][0] * inv, accT[dkf][qf][1] * inv);
            o[1] = pk2(accT[dkf][qf][2] * inv, accT[dkf][qf][3] * inv);
            long addr = ((long)b * Lseq + q) * Dm + h * Dk + dk0;
            *(u32x2*)(Ctx + addr) = o;
        }
    }
}

// ---------------------------------------------------------------------------
extern "C" void kernel_launch(void* const* d_in, const int* in_sizes, int n_in,
                              void* d_out, int out_size, void* d_ws, size_t ws_size,
                              hipStream_t stream)
{
    const float* query = (const float*)d_in[0];
    const float* key_  = (const float*)d_in[1];
    const float* value = (const float*)d_in[2];
    const float* Wq = (const float*)d_in[3];
    const float* bq = (const float*)d_in[4];
    const float* Wk = (const float*)d_in[5];
    const float* bk = (const float*)d_in[6];
    const float* Wv = (const float*)d_in[7];
    const float* bv = (const float*)d_in[8];
    const float* Wo = (const float*)d_in[9];
    const float* bo = (const float*)d_in[10];
    // d_in[11] = attn_mask (bool causal) — derived from indices instead.

    float* out = (float*)d_out;
    const size_t tens = (size_t)Bsz * Lseq * Dm;   // 8,388,608
    const size_t wTot = (size_t)Dm * Dm;           // 1,048,576
    // ws layout (4*tens*2B = 67.1 MB, proven available):
    u16* Qb = (u16*)d_ws;        // bf16 [B,H,L,DK] (Q pre-scaled)
    u16* Kb = Qb + tens;
    u16* Vb = Kb + tens;
    u16* Cx = Vb + tens;         // attn output [B,L,D]
    // weight bf16 buffers alias dead regions:
    u16* Wqb = Cx;               // Wq/Wk/Wv (contiguous) live in Cx slot until attn
    u16* Wkb = Wqb + wTot;
    u16* Wvb = Wkb + wTot;
    u16* Wob = Qb;               // converted AFTER attn (Qb dead by then)

    dim3 blk(256), g(64, 8), gq(64, 24);
    const int n8w = (int)(wTot / 8);
    const int gw = (n8w + 255) / 256;

    cvt_f2b<<<gw, blk, 0, stream>>>(Wq, Wqb, n8w);
    cvt_f2b<<<gw, blk, 0, stream>>>(Wk, Wkb, n8w);
    cvt_f2b<<<gw, blk, 0, stream>>>(Wv, Wvb, n8w);
    gemm_qkv<<<gq, blk, 0, stream>>>(query, key_, value, Wqb, bq, bk, bv, Qb);
    attn_fwd<<<dim3(Bsz * Hn, Lseq / 128), blk, 0, stream>>>(Qb, Kb, Vb, Cx);
    cvt_f2b<<<gw, blk, 0, stream>>>(Wo, Wob, n8w);
    gemm_glds<<<g, blk, 0, stream>>>(Cx, Wob, bo, out, 1.0f);
}